// Round 10
// baseline (514.132 us; speedup 1.0000x reference)
//
#include <hip/hip_runtime.h>
#include <math.h>

#define NP 401            // tokens incl. CLS (400 patches, side=20, add=0)
#define DIM 512
#define LN_EPS 1e-5f
#define ATT_SCALE 0.125f
#define CPB_M 16384       // angle-table resolution
#define TSTRIDE (CPB_M + 64)
#define PQS (401L * 1536) // qkv partial slice stride
#define PVS (401L * 512)  // pv / proj partial slice stride

// ---------------------------------------------------------------------------
// 64x64-tile GEMM body: 256 thr, 4x4 micro-tile, K-chunk 16, register
// double-buffered staging via caller-supplied loaders.
// ---------------------------------------------------------------------------
template<bool TB, typename LA, typename LB>
__device__ __forceinline__ void gemm64(
    int kBeg, int kEnd, int tid,
    float (*as)[68], float (*bs)[68], float (&acc)[4][4],
    LA&& loadA, LB&& loadB)
{
    float aR[4], bR[4];
    loadA(kBeg, aR);
    loadB(kBeg, bR);
    for (int k0 = kBeg; k0 < kEnd; k0 += 16) {
        const int arow = tid >> 2, aq = tid & 3;
        as[aq * 4 + 0][arow] = aR[0];
        as[aq * 4 + 1][arow] = aR[1];
        as[aq * 4 + 2][arow] = aR[2];
        as[aq * 4 + 3][arow] = aR[3];
        if (!TB) {
            *(float4*)&bs[tid >> 4][(tid & 15) * 4] =
                make_float4(bR[0], bR[1], bR[2], bR[3]);
        } else {
            bs[aq * 4 + 0][arow] = bR[0];
            bs[aq * 4 + 1][arow] = bR[1];
            bs[aq * 4 + 2][arow] = bR[2];
            bs[aq * 4 + 3][arow] = bR[3];
        }
        __syncthreads();
        float nA[4] = {0.f,0.f,0.f,0.f}, nB[4] = {0.f,0.f,0.f,0.f};
        if (k0 + 16 < kEnd) { loadA(k0 + 16, nA); loadB(k0 + 16, nB); }
        const int tx = tid & 15, ty = tid >> 4;
        #pragma unroll
        for (int kk = 0; kk < 16; ++kk) {
            float4 a4 = *(const float4*)&as[kk][ty * 4];
            float4 b4 = *(const float4*)&bs[kk][tx * 4];
            float av[4] = {a4.x, a4.y, a4.z, a4.w};
            float bv[4] = {b4.x, b4.y, b4.z, b4.w};
            #pragma unroll
            for (int r = 0; r < 4; ++r)
                #pragma unroll
                for (int c = 0; c < 4; ++c)
                    acc[r][c] = fmaf(av[r], bv[c], acc[r][c]);
        }
        __syncthreads();
        #pragma unroll
        for (int j = 0; j < 4; ++j) { aR[j] = nA[j]; bR[j] = nB[j]; }
    }
}

// ---------------------------------------------------------------------------
// Generic split-K GEMM: P[sk] = A[:, slice] @ B[slice, :]  (raw partials)
// ---------------------------------------------------------------------------
__global__ __launch_bounds__(256) void gemm_split_kernel(
    const float* __restrict__ A, int lda,
    const float* __restrict__ B, int ldb,
    float* __restrict__ P, int ldc, long slice,
    int M, int N, int K, int skN)
{
    __shared__ float as[16][68], bs[16][68];
    const int tid = threadIdx.x;
    const int m0 = blockIdx.x * 64, n0 = blockIdx.y * 64;
    const int sk = blockIdx.z;
    const int KS = ((K + skN * 16 - 1) / (skN * 16)) * 16;
    const int kBeg = sk * KS;
    const int kEnd = (kBeg + KS < K) ? kBeg + KS : K;
    float acc[4][4] = {};

    auto loadA = [&](int k0, float r[4]) {
        r[0] = r[1] = r[2] = r[3] = 0.f;
        int gm = m0 + (tid >> 2);
        if (gm >= M) return;
        int gk = k0 + (tid & 3) * 4;
        const float* p = A + (long)gm * lda + gk;
        if (gk + 3 < kEnd) {
            float4 v = *(const float4*)p;
            r[0] = v.x; r[1] = v.y; r[2] = v.z; r[3] = v.w;
        } else {
            #pragma unroll
            for (int j = 0; j < 4; ++j) if (gk + j < kEnd) r[j] = p[j];
        }
    };
    auto loadB = [&](int k0, float r[4]) {
        r[0] = r[1] = r[2] = r[3] = 0.f;
        int gk = k0 + (tid >> 4);
        if (gk >= kEnd) return;
        int gn = n0 + (tid & 15) * 4;
        const float* p = B + (long)gk * ldb + gn;
        float4 v = *(const float4*)p;
        r[0] = v.x; r[1] = v.y; r[2] = v.z; r[3] = v.w;
    };
    if (kBeg < kEnd)
        gemm64<false>(kBeg, kEnd, tid, as, bs, acc, loadA, loadB);

    float* C = P + (long)sk * slice;
    const int tx = tid & 15, ty = tid >> 4;
    #pragma unroll
    for (int r = 0; r < 4; ++r) {
        int m = m0 + ty * 4 + r;
        if (m >= M) continue;
        *(float4*)&C[(long)m * ldc + n0 + tx * 4] =
            make_float4(acc[r][0], acc[r][1], acc[r][2], acc[r][3]);
    }
}

// ---------------------------------------------------------------------------
// Slice reduce: out[i] = sum_sk P[sk][i] (+ bias[i % N]). float4/thread.
// ---------------------------------------------------------------------------
__global__ __launch_bounds__(256) void reduce_kernel(
    const float* __restrict__ P, long slice, int skN,
    const float* __restrict__ bias, float* __restrict__ out,
    int total, int N)
{
    int idx = (blockIdx.x * 256 + threadIdx.x) * 4;
    if (idx >= total) return;
    float4 s = *(const float4*)(P + idx);
    for (int k = 1; k < skN; ++k) {
        float4 p = *(const float4*)(P + (long)k * slice + idx);
        s.x += p.x; s.y += p.y; s.z += p.z; s.w += p.w;
    }
    if (bias) {
        const float4 b = *(const float4*)(bias + (idx % N));
        s.x += b.x; s.y += b.y; s.z += b.z; s.w += b.w;
    }
    *(float4*)(out + idx) = s;
}

// ---------------------------------------------------------------------------
// Flash attention (layer 1): grid (13 q-tiles of 32, 8 heads), 256 thr.
// Per chunk of 64 keys: stage K^T,V in LDS; 32x64 scores by outer product;
// CPB bias interp; online softmax (m,l in registers per row-pair owner);
// PV accumulate. Final O/l -> dense att[401][512]. No S materialization.
// ---------------------------------------------------------------------------
__global__ __launch_bounds__(256) void flash_kernel(
    const float* __restrict__ qkv,
    const int* __restrict__ pm, const float* __restrict__ pf,
    const float* __restrict__ T, float* __restrict__ att)
{
    __shared__ float qsT[64 * 32];   // [d][i]
    __shared__ float kT[64 * 68];    // [d][j]
    __shared__ float vs[64 * 68];    // [j][d]
    __shared__ float psT[64 * 34];   // [j][i]
    const int tid = threadIdx.x;
    const int m0 = blockIdx.x * 32, h = blockIdx.y;
    const int tx = tid & 15, ty = tid >> 4;
    const int i0 = ty * 2;

    // stage Q tile transposed (once)
    {
        int i = tid >> 3, dq = (tid & 7) * 8;
        int gm = m0 + i;
        float4 a = make_float4(0, 0, 0, 0), b = make_float4(0, 0, 0, 0);
        if (gm <= 400) {
            const float* p = qkv + (long)gm * 1536 + h * 64 + dq;
            a = *(const float4*)p;
            b = *(const float4*)(p + 4);
        }
        qsT[(dq + 0) * 32 + i] = a.x;
        qsT[(dq + 1) * 32 + i] = a.y;
        qsT[(dq + 2) * 32 + i] = a.z;
        qsT[(dq + 3) * 32 + i] = a.w;
        qsT[(dq + 4) * 32 + i] = b.x;
        qsT[(dq + 5) * 32 + i] = b.y;
        qsT[(dq + 6) * 32 + i] = b.z;
        qsT[(dq + 7) * 32 + i] = b.w;
    }

    float O[2][4] = {{0.f,0.f,0.f,0.f},{0.f,0.f,0.f,0.f}};
    float mr[2] = {-INFINITY, -INFINITY};
    float lr[2] = {0.f, 0.f};
    const float* Tt = T + (long)h * TSTRIDE;
    const int ig0 = (m0 + i0     <= 400) ? m0 + i0     : 400;  // clamp: keep
    const int ig1 = (m0 + i0 + 1 <= 400) ? m0 + i0 + 1 : 400;  // pm in-bounds

    for (int c = 0; c < 7; ++c) {
        const int kBeg = c * 64;
        __syncthreads();   // protect LDS reuse from previous chunk's PV
        {   // stage K^T and V
            int j = tid >> 2, dq = (tid & 3) * 16;
            int gj = kBeg + j;
            float4 k4[4], v4[4];
            #pragma unroll
            for (int q = 0; q < 4; ++q) {
                k4[q] = make_float4(0, 0, 0, 0);
                v4[q] = make_float4(0, 0, 0, 0);
            }
            if (gj <= 400) {
                const float* kp = qkv + (long)gj * 1536 + 512 + h * 64 + dq;
                const float* vp = kp + 512;
                #pragma unroll
                for (int q = 0; q < 4; ++q) {
                    k4[q] = *(const float4*)(kp + q * 4);
                    v4[q] = *(const float4*)(vp + q * 4);
                }
            }
            #pragma unroll
            for (int q = 0; q < 4; ++q) {
                kT[(dq + q * 4 + 0) * 68 + j] = k4[q].x;
                kT[(dq + q * 4 + 1) * 68 + j] = k4[q].y;
                kT[(dq + q * 4 + 2) * 68 + j] = k4[q].z;
                kT[(dq + q * 4 + 3) * 68 + j] = k4[q].w;
                *(float4*)&vs[j * 68 + dq + q * 4] = v4[q];
            }
        }
        __syncthreads();

        // scores: s[r][c4] over d
        float s0[4] = {0.f,0.f,0.f,0.f}, s1[4] = {0.f,0.f,0.f,0.f};
        #pragma unroll
        for (int d = 0; d < 64; ++d) {
            float2 q2 = *(const float2*)&qsT[d * 32 + i0];
            float4 k4 = *(const float4*)&kT[d * 68 + tx * 4];
            s0[0] = fmaf(q2.x, k4.x, s0[0]);
            s0[1] = fmaf(q2.x, k4.y, s0[1]);
            s0[2] = fmaf(q2.x, k4.z, s0[2]);
            s0[3] = fmaf(q2.x, k4.w, s0[3]);
            s1[0] = fmaf(q2.y, k4.x, s1[0]);
            s1[1] = fmaf(q2.y, k4.y, s1[1]);
            s1[2] = fmaf(q2.y, k4.z, s1[2]);
            s1[3] = fmaf(q2.y, k4.w, s1[3]);
        }
        // CPB bias + scale
        #pragma unroll
        for (int cc = 0; cc < 4; ++cc) {
            int jg = kBeg + tx * 4 + cc;
            if (jg <= 400) {
                int id0 = ig0 * 416 + jg, id1 = ig1 * 416 + jg;
                int ma = pm[id0], mb = pm[id1];
                float fa = pf[id0], fb = pf[id1];
                float a0 = Tt[ma], a1 = Tt[ma + 1];
                float b0 = Tt[mb], b1 = Tt[mb + 1];
                s0[cc] = fmaf(s0[cc], ATT_SCALE, fmaf(fa, a1 - a0, a0));
                s1[cc] = fmaf(s1[cc], ATT_SCALE, fmaf(fb, b1 - b0, b0));
            } else {
                s0[cc] = -INFINITY;
                s1[cc] = -INFINITY;
            }
        }
        // online softmax update (rows i0, i0+1); 16-lane groups share a row
        #pragma unroll
        for (int r = 0; r < 2; ++r) {
            float* s = r ? s1 : s0;
            float cmax = fmaxf(fmaxf(s[0], s[1]), fmaxf(s[2], s[3]));
            cmax = fmaxf(cmax, __shfl_xor(cmax, 1));
            cmax = fmaxf(cmax, __shfl_xor(cmax, 2));
            cmax = fmaxf(cmax, __shfl_xor(cmax, 4));
            cmax = fmaxf(cmax, __shfl_xor(cmax, 8));
            float mn = fmaxf(mr[r], cmax);
            float al = __expf(mr[r] - mn);
            float rs = 0.f;
            #pragma unroll
            for (int cc = 0; cc < 4; ++cc) {
                float e = __expf(s[cc] - mn);
                s[cc] = e;
                rs += e;
            }
            rs += __shfl_xor(rs, 1);
            rs += __shfl_xor(rs, 2);
            rs += __shfl_xor(rs, 4);
            rs += __shfl_xor(rs, 8);
            lr[r] = lr[r] * al + rs;
            mr[r] = mn;
            #pragma unroll
            for (int cc = 0; cc < 4; ++cc) {
                O[r][cc] *= al;
                psT[(tx * 4 + cc) * 34 + i0 + r] = s[cc];
            }
        }
        __syncthreads();

        // PV accumulate: O[r][d4] += p[r][j] * v[j][d4]
        #pragma unroll 4
        for (int j = 0; j < 64; ++j) {
            float2 p2 = *(const float2*)&psT[j * 34 + i0];
            float4 v4 = *(const float4*)&vs[j * 68 + tx * 4];
            O[0][0] = fmaf(p2.x, v4.x, O[0][0]);
            O[0][1] = fmaf(p2.x, v4.y, O[0][1]);
            O[0][2] = fmaf(p2.x, v4.z, O[0][2]);
            O[0][3] = fmaf(p2.x, v4.w, O[0][3]);
            O[1][0] = fmaf(p2.y, v4.x, O[1][0]);
            O[1][1] = fmaf(p2.y, v4.y, O[1][1]);
            O[1][2] = fmaf(p2.y, v4.z, O[1][2]);
            O[1][3] = fmaf(p2.y, v4.w, O[1][3]);
        }
    }

    #pragma unroll
    for (int r = 0; r < 2; ++r) {
        int ig = m0 + i0 + r;
        if (ig > 400) continue;
        float inv = 1.f / lr[r];
        *(float4*)&att[(long)ig * 512 + h * 64 + tx * 4] =
            make_float4(O[r][0] * inv, O[r][1] * inv,
                        O[r][2] * inv, O[r][3] * inv);
    }
}

// ---------------------------------------------------------------------------
// proj (layer 1), split-K8, dense att. grid (7,8,8).
// ---------------------------------------------------------------------------
__global__ __launch_bounds__(256) void proj_kernel(
    const float* __restrict__ att, const float* __restrict__ projw,
    float* __restrict__ Pp)
{
    __shared__ float as[16][68], bs[16][68];
    const int tid = threadIdx.x;
    const int m0 = blockIdx.x * 64, n0 = blockIdx.y * 64, sk = blockIdx.z;
    const int kBeg = sk * 64, kEnd = kBeg + 64;
    float acc[4][4] = {};

    auto loadA = [&](int k0, float r[4]) {
        r[0] = r[1] = r[2] = r[3] = 0.f;
        int gm = m0 + (tid >> 2);
        if (gm > 400) return;
        int gk = k0 + (tid & 3) * 4;
        float4 v = *(const float4*)(att + (long)gm * 512 + gk);
        r[0]=v.x; r[1]=v.y; r[2]=v.z; r[3]=v.w;
    };
    auto loadB = [&](int k0, float r[4]) {
        int gk = k0 + (tid >> 4);
        int gn = n0 + (tid & 15) * 4;
        float4 v = *(const float4*)(projw + (long)gk * 512 + gn);
        r[0]=v.x; r[1]=v.y; r[2]=v.z; r[3]=v.w;
    };
    gemm64<false>(kBeg, kEnd, tid, as, bs, acc, loadA, loadB);

    float* C = Pp + (long)sk * PVS;
    const int tx = tid & 15, ty = tid >> 4;
    #pragma unroll
    for (int r = 0; r < 4; ++r) {
        int m = m0 + ty * 4 + r;
        if (m > 400) continue;
        *(float4*)&C[(long)m * 512 + n0 + tx * 4] =
            make_float4(acc[r][0], acc[r][1], acc[r][2], acc[r][3]);
    }
}

// ---------------------------------------------------------------------------
// Per-row split-K reduce + epilogue + LayerNorm. grid 401.
// ---------------------------------------------------------------------------
__global__ __launch_bounds__(256) void rowfuse_kernel(
    const float* __restrict__ P, long slice, int skN, int rowOff,
    const float* __restrict__ bias, int doRelu,
    const float* __restrict__ resid, const float* __restrict__ cls,
    float* __restrict__ h0,
    const float* __restrict__ g, const float* __restrict__ b,
    float* __restrict__ xln)
{
    const int r = blockIdx.x, t = threadIdx.x;
    float v0, v1;
    if (cls && r == 0) {
        v0 = cls[t]; v1 = cls[t + 256];
    } else {
        const float* p = P + (long)(r - rowOff) * DIM;
        v0 = bias[t]; v1 = bias[t + 256];
        for (int k = 0; k < skN; ++k) {
            v0 += p[(long)k * slice + t];
            v1 += p[(long)k * slice + t + 256];
        }
        if (resid) {
            v0 += resid[(long)r * DIM + t];
            v1 += resid[(long)r * DIM + t + 256];
        }
        if (doRelu) { v0 = fmaxf(v0, 0.f); v1 = fmaxf(v1, 0.f); }
    }
    h0[(long)r * DIM + t] = v0;
    h0[(long)r * DIM + t + 256] = v1;

    float s = v0 + v1, sq = v0 * v0 + v1 * v1;
    #pragma unroll
    for (int off = 32; off > 0; off >>= 1) {
        s += __shfl_down(s, off);
        sq += __shfl_down(sq, off);
    }
    __shared__ float ps[4], pq[4];
    int w = t >> 6, lane = t & 63;
    if (lane == 0) { ps[w] = s; pq[w] = sq; }
    __syncthreads();
    float Sm = ps[0] + ps[1] + ps[2] + ps[3];
    float Q = pq[0] + pq[1] + pq[2] + pq[3];
    float mean = Sm * (1.f / DIM);
    float var = Q * (1.f / DIM) - mean * mean;
    float inv = rsqrtf(var + LN_EPS);
    xln[(long)r * DIM + t]       = (v0 - mean) * inv * g[t] + b[t];
    xln[(long)r * DIM + t + 256] = (v1 - mean) * inv * g[t + 256] + b[t + 256];
}

// ---------------------------------------------------------------------------
// CLS tail (layer 2): full CLS attention (all 8 heads) + proj + residual
// + LN + fc2 in ONE block. grid 1 x 256 thr.
// ---------------------------------------------------------------------------
__global__ __launch_bounds__(256) void cls_tail_kernel(
    const float* __restrict__ qkv,
    const int* __restrict__ pm, const float* __restrict__ pf,
    const float* __restrict__ T,
    const float* __restrict__ projw, const float* __restrict__ projb,
    const float* __restrict__ h0,
    const float* __restrict__ g, const float* __restrict__ b,
    const float* __restrict__ fc2w, const float* __restrict__ fc2b,
    float* __restrict__ out)
{
    const int tid = threadIdx.x;
    const int w = tid >> 6, lane = tid & 63;
    __shared__ float q0[64], sc[512], av[512], red[4][64], rr[8];

    for (int h = 0; h < 8; ++h) {
        if (tid < 64) q0[tid] = qkv[h * 64 + tid];
        __syncthreads();
        const float* Tt = T + (long)h * TSTRIDE;
        #pragma unroll
        for (int jj = 0; jj < 2; ++jj) {
            int j = tid + jj * 256;
            if (j < NP) {
                const float* kp = qkv + (long)j * 1536 + 512 + h * 64;
                float dot = 0.f;
                #pragma unroll
                for (int d = 0; d < 64; d += 4) {
                    float4 kv = *(const float4*)(kp + d);
                    float4 qq = *(const float4*)(q0 + d);
                    dot = fmaf(qq.x, kv.x, dot);
                    dot = fmaf(qq.y, kv.y, dot);
                    dot = fmaf(qq.z, kv.z, dot);
                    dot = fmaf(qq.w, kv.w, dot);
                }
                int mm = pm[j];
                float fr = pf[j];
                float t0 = Tt[mm], t1 = Tt[mm + 1];
                sc[j] = fmaf(dot, ATT_SCALE, fmaf(fr, t1 - t0, t0));
            } else if (j < 512) {
                sc[j] = -INFINITY;
            }
        }
        __syncthreads();
        float mx = fmaxf(sc[tid], sc[tid + 256]);
        #pragma unroll
        for (int off = 32; off > 0; off >>= 1)
            mx = fmaxf(mx, __shfl_xor(mx, off));
        if (lane == 0) rr[w] = mx;
        __syncthreads();
        float M = fmaxf(fmaxf(rr[0], rr[1]), fmaxf(rr[2], rr[3]));
        float e0 = (tid < NP) ? __expf(sc[tid] - M) : 0.f;
        float e1 = (tid + 256 < NP) ? __expf(sc[tid + 256] - M) : 0.f;
        float s = e0 + e1;
        #pragma unroll
        for (int off = 32; off > 0; off >>= 1)
            s += __shfl_xor(s, off);
        if (lane == 0) rr[4 + w] = s;
        __syncthreads();
        float inv = 1.f / (rr[4] + rr[5] + rr[6] + rr[7]);
        sc[tid] = e0 * inv;
        sc[tid + 256] = e1 * inv;
        __syncthreads();
        float acc = 0.f;
        for (int j = w; j < NP; j += 4)
            acc = fmaf(sc[j], qkv[(long)j * 1536 + 1024 + h * 64 + lane], acc);
        red[w][lane] = acc;
        __syncthreads();
        if (tid < 64)
            av[h * 64 + tid] =
                red[0][tid] + red[1][tid] + red[2][tid] + red[3][tid];
        __syncthreads();
    }

    // proj columns tid, tid+256 + residual + LN + fc2
    float a0 = projb[tid], a1 = projb[tid + 256];
    #pragma unroll 8
    for (int k = 0; k < 512; ++k) {
        float avk = av[k];
        a0 = fmaf(avk, projw[(long)k * 512 + tid], a0);
        a1 = fmaf(avk, projw[(long)k * 512 + tid + 256], a1);
    }
    float v0 = h0[tid] + a0, v1 = h0[tid + 256] + a1;
    float s = v0 + v1, sq = v0 * v0 + v1 * v1;
    #pragma unroll
    for (int off = 32; off > 0; off >>= 1) {
        s += __shfl_down(s, off);
        sq += __shfl_down(sq, off);
    }
    __shared__ float ps[4], pq[4], pc0[4], pc1[4];
    if (lane == 0) { ps[w] = s; pq[w] = sq; }
    __syncthreads();
    float Sm = ps[0] + ps[1] + ps[2] + ps[3];
    float Q = pq[0] + pq[1] + pq[2] + pq[3];
    float mean = Sm * (1.f / DIM);
    float var = Q * (1.f / DIM) - mean * mean;
    float inv = rsqrtf(var + LN_EPS);
    float n0 = (v0 - mean) * inv * g[tid] + b[tid];
    float n1 = (v1 - mean) * inv * g[tid + 256] + b[tid + 256];
    float c0 = n0 * fc2w[tid * 2]     + n1 * fc2w[(tid + 256) * 2];
    float c1 = n0 * fc2w[tid * 2 + 1] + n1 * fc2w[(tid + 256) * 2 + 1];
    #pragma unroll
    for (int off = 32; off > 0; off >>= 1) {
        c0 += __shfl_down(c0, off);
        c1 += __shfl_down(c1, off);
    }
    if (lane == 0) { pc0[w] = c0; pc1[w] = c1; }
    __syncthreads();
    if (tid == 0) {
        out[0] = pc0[0] + pc0[1] + pc0[2] + pc0[3] + fc2b[0];
        out[1] = pc1[0] + pc1[1] + pc1[2] + pc1[3] + fc2b[1];
    }
}

// ---------------------------------------------------------------------------
// Mega init: [0,896) fc1 split-K16 -> Pp; [896,1410) CPB angle tables;
// [1410,2039) pair -> (angle idx, frac).
// ---------------------------------------------------------------------------
__global__ __launch_bounds__(256) void mega_kernel(
    const float* __restrict__ hin, const float* __restrict__ fc1_w,
    const float* __restrict__ w1_0, const float* __restrict__ b1_0,
    const float* __restrict__ w2_0, const float* __restrict__ b2_0,
    const float* __restrict__ w1_1, const float* __restrict__ b1_1,
    const float* __restrict__ w2_1, const float* __restrict__ b2_1,
    const float* __restrict__ coords,
    float* __restrict__ Pp, float* __restrict__ T,
    int* __restrict__ pm, float* __restrict__ pf)
{
    __shared__ float smem[2176];
    float (*as)[68] = (float(*)[68])smem;
    float (*bs)[68] = (float(*)[68])(smem + 1088);
    float (*red)[64][8] = (float(*)[64][8])smem;
    const int bid = blockIdx.x, tid = threadIdx.x;

    if (bid < 896) {
        int sk = bid / 56, rem = bid % 56;
        int m0 = (rem % 7) * 64, n0 = (rem / 7) * 64;
        int kBeg = sk * 64, kEnd = kBeg + 64;
        float acc[4][4] = {};
        auto loadA = [&](int k0, float r[4]) {
            r[0]=r[1]=r[2]=r[3]=0.f;
            int gm = m0 + (tid >> 2);
            if (gm >= 400) return;
            int gk = k0 + (tid & 3) * 4;
            float4 v = *(const float4*)(hin + (long)gm * 1024 + gk);
            r[0]=v.x; r[1]=v.y; r[2]=v.z; r[3]=v.w;
        };
        auto loadB = [&](int k0, float r[4]) {
            int gk = k0 + (tid >> 4);
            int gn = n0 + (tid & 15) * 4;
            float4 v = *(const float4*)(fc1_w + (long)gk * 512 + gn);
            r[0]=v.x; r[1]=v.y; r[2]=v.z; r[3]=v.w;
        };
        gemm64<false>(kBeg, kEnd, tid, as, bs, acc, loadA, loadB);
        float* C = Pp + (long)sk * PVS;
        const int tx = tid & 15, ty = tid >> 4;
        #pragma unroll
        for (int r = 0; r < 4; ++r) {
            int m = m0 + ty * 4 + r;
            if (m >= 400) continue;
            *(float4*)&C[(long)m * 512 + n0 + tx * 4] =
                make_float4(acc[r][0], acc[r][1], acc[r][2], acc[r][3]);
        }
    } else if (bid < 1410) {
        int tb = bid - 896;
        int z = tb / 257, ab = tb % 257;
        const float* w1 = z ? w1_1 : w1_0;
        const float* b1 = z ? b1_1 : b1_0;
        const float* w2 = z ? w2_1 : w2_0;
        const float* b2 = z ? b2_1 : b2_0;
        const int lane = tid & 63, wv = tid >> 6;
        float ca = 0.f, sa = 0.f;
        if (ab != 256) {
            float th = fmaf((float)(ab * 64 + lane),
                            (float)(2.0 * M_PI / CPB_M), -(float)M_PI);
            sincosf(th, &sa, &ca);
        } else if (lane == 0) {
            sincosf((float)M_PI, &sa, &ca);  // wrap row; lanes>0 zero-vec
        }
        float a8[8] = {};
        const int kbeg = wv * 128;
        #pragma unroll 4
        for (int k = kbeg; k < kbeg + 128; ++k) {
            float hk = fmaxf(fmaf(ca, w1[k],
                                  fmaf(sa, w1[512 + k], b1[k])), 0.f);
            #pragma unroll
            for (int h2 = 0; h2 < 8; ++h2)
                a8[h2] = fmaf(hk, w2[k * 8 + h2], a8[h2]);
        }
        #pragma unroll
        for (int h2 = 0; h2 < 8; ++h2) red[wv][lane][h2] = a8[h2];
        __syncthreads();
        if (tid < 64) {
            int aidx = ab * 64 + tid;
            #pragma unroll
            for (int h2 = 0; h2 < 8; ++h2)
                T[(long)(z * 8 + h2) * TSTRIDE + aidx] =
                    red[0][tid][h2] + red[1][tid][h2] +
                    red[2][tid][h2] + red[3][tid][h2] + b2[h2];
        }
    } else {
        int p = (bid - 1410) * 256 + tid;
        if (p < NP * NP) {
            int i = p / NP, j = p - i * NP;
            float xi = (i == 0) ? 0.f : coords[(i - 1) * 2];
            float yi = (i == 0) ? 0.f : coords[(i - 1) * 2 + 1];
            float xj = (j == 0) ? 0.f : coords[(j - 1) * 2];
            float yj = (j == 0) ? 0.f : coords[(j - 1) * 2 + 1];
            float rx = xi - xj, ry = yi - yj;
            int mm; float fr;
            if (rx == 0.f && ry == 0.f) {
                mm = CPB_M + 1; fr = 0.f;
            } else {
                float x = (atan2f(ry, rx) + 3.14159265358979f)
                          * (float)(CPB_M / (2.0 * M_PI));
                int mi = (int)x;
                fr = x - (float)mi;
                mm = (mi >= CPB_M) ? mi - CPB_M : mi;
            }
            pm[i * 416 + j] = mm;
            pf[i * 416 + j] = fr;
        }
    }
}

// ---------------------------------------------------------------------------
extern "C" void kernel_launch(void* const* d_in, const int* in_sizes, int n_in,
                              void* d_out, int out_size, void* d_ws, size_t ws_size,
                              hipStream_t stream)
{
    const float* coords = (const float*)d_in[1];
    float* ws = (float*)d_ws;
    float* h0   = ws;                    ws += 401L * 512;
    float* xln  = ws;                    ws += 401L * 512;
    float* T    = ws;                    ws += 16L * TSTRIDE;
    int*   pm   = (int*)ws;              ws += 401L * 416;
    float* pf   = ws;                    ws += 401L * 416;
    float* Pq   = ws;                    ws += 4L * PQS;
    float* qkv  = ws;                    ws += 401L * 1536;
    float* att  = ws;                    ws += 401L * 512;
    float* Pp   = ws;                    ws += 16L * PVS;

    // phase 0: fc1 (K16) + both CPB angle tables + pair->angle map
    mega_kernel<<<2039, 256, 0, stream>>>(
        (const float*)d_in[0], (const float*)d_in[2],
        (const float*)d_in[7],  (const float*)d_in[8],
        (const float*)d_in[9],  (const float*)d_in[10],
        (const float*)d_in[17], (const float*)d_in[18],
        (const float*)d_in[19], (const float*)d_in[20],
        coords, Pp, T, pm, pf);

    // fc1 reduce + relu + cls + LN(l1) -> h0, xln
    rowfuse_kernel<<<401, 256, 0, stream>>>(
        Pp, PVS, 16, 1, (const float*)d_in[3], 1, nullptr,
        (const float*)d_in[4], h0,
        (const float*)d_in[5], (const float*)d_in[6], xln);

    // -------- layer 1 (full attention, flash) --------
    gemm_split_kernel<<<dim3(7, 24, 4), 256, 0, stream>>>(
        xln, 512, (const float*)d_in[11], 1536, Pq, 1536, PQS,
        401, 1536, 512, 4);
    reduce_kernel<<<602, 256, 0, stream>>>(
        Pq, PQS, 4, (const float*)d_in[12], qkv, 401 * 1536, 1536);
    flash_kernel<<<dim3(13, 8), 256, 0, stream>>>(qkv, pm, pf, T, att);
    proj_kernel<<<dim3(7, 8, 8), 256, 0, stream>>>(
        att, (const float*)d_in[13], Pp);
    rowfuse_kernel<<<401, 256, 0, stream>>>(
        Pp, PVS, 8, 0, (const float*)d_in[14], 0, h0, nullptr, h0,
        (const float*)d_in[15], (const float*)d_in[16], xln);

    // -------- layer 2 (CLS row only) --------
    gemm_split_kernel<<<dim3(7, 24, 4), 256, 0, stream>>>(
        xln, 512, (const float*)d_in[21], 1536, Pq, 1536, PQS,
        401, 1536, 512, 4);
    reduce_kernel<<<602, 256, 0, stream>>>(
        Pq, PQS, 4, (const float*)d_in[22], qkv, 401 * 1536, 1536);
    cls_tail_kernel<<<1, 256, 0, stream>>>(
        qkv, pm, pf, T + 8L * TSTRIDE,
        (const float*)d_in[23], (const float*)d_in[24], h0,
        (const float*)d_in[25], (const float*)d_in[26],
        (const float*)d_in[27], (const float*)d_in[28], (float*)d_out);
}

// Round 11
// 283.451 us; speedup vs baseline: 1.8138x; 1.8138x over previous
//
#include <hip/hip_runtime.h>
#include <math.h>

#define NP 401            // tokens incl. CLS (400 patches, side=20, add=0)
#define DIM 512
#define LN_EPS 1e-5f
#define ATT_SCALE 0.125f
#define CPB_M 16384       // angle-table resolution
#define TSTRIDE (CPB_M + 64)
#define PQS (401L * 1536) // qkv partial slice stride
#define PVS (401L * 512)  // pv / proj partial slice stride

// ---------------------------------------------------------------------------
// 64x64-tile GEMM body: 256 thr, 4x4 micro-tile, K-chunk 16, register
// double-buffered staging via caller-supplied loaders.
// ---------------------------------------------------------------------------
template<bool TB, typename LA, typename LB>
__device__ __forceinline__ void gemm64(
    int kBeg, int kEnd, int tid,
    float (*as)[68], float (*bs)[68], float (&acc)[4][4],
    LA&& loadA, LB&& loadB)
{
    float aR[4], bR[4];
    loadA(kBeg, aR);
    loadB(kBeg, bR);
    for (int k0 = kBeg; k0 < kEnd; k0 += 16) {
        const int arow = tid >> 2, aq = tid & 3;
        as[aq * 4 + 0][arow] = aR[0];
        as[aq * 4 + 1][arow] = aR[1];
        as[aq * 4 + 2][arow] = aR[2];
        as[aq * 4 + 3][arow] = aR[3];
        if (!TB) {
            *(float4*)&bs[tid >> 4][(tid & 15) * 4] =
                make_float4(bR[0], bR[1], bR[2], bR[3]);
        } else {
            bs[aq * 4 + 0][arow] = bR[0];
            bs[aq * 4 + 1][arow] = bR[1];
            bs[aq * 4 + 2][arow] = bR[2];
            bs[aq * 4 + 3][arow] = bR[3];
        }
        __syncthreads();
        float nA[4] = {0.f,0.f,0.f,0.f}, nB[4] = {0.f,0.f,0.f,0.f};
        if (k0 + 16 < kEnd) { loadA(k0 + 16, nA); loadB(k0 + 16, nB); }
        const int tx = tid & 15, ty = tid >> 4;
        #pragma unroll
        for (int kk = 0; kk < 16; ++kk) {
            float4 a4 = *(const float4*)&as[kk][ty * 4];
            float4 b4 = *(const float4*)&bs[kk][tx * 4];
            float av[4] = {a4.x, a4.y, a4.z, a4.w};
            float bv[4] = {b4.x, b4.y, b4.z, b4.w};
            #pragma unroll
            for (int r = 0; r < 4; ++r)
                #pragma unroll
                for (int c = 0; c < 4; ++c)
                    acc[r][c] = fmaf(av[r], bv[c], acc[r][c]);
        }
        __syncthreads();
        #pragma unroll
        for (int j = 0; j < 4; ++j) { aR[j] = nA[j]; bR[j] = nB[j]; }
    }
}

// ---------------------------------------------------------------------------
// Generic split-K GEMM: P[sk] = A[:, slice] @ B[slice, :]  (raw partials)
// ---------------------------------------------------------------------------
__global__ __launch_bounds__(256) void gemm_split_kernel(
    const float* __restrict__ A, int lda,
    const float* __restrict__ B, int ldb,
    float* __restrict__ P, int ldc, long slice,
    int M, int N, int K, int skN)
{
    __shared__ float as[16][68], bs[16][68];
    const int tid = threadIdx.x;
    const int m0 = blockIdx.x * 64, n0 = blockIdx.y * 64;
    const int sk = blockIdx.z;
    const int KS = ((K + skN * 16 - 1) / (skN * 16)) * 16;
    const int kBeg = sk * KS;
    const int kEnd = (kBeg + KS < K) ? kBeg + KS : K;
    float acc[4][4] = {};

    auto loadA = [&](int k0, float r[4]) {
        r[0] = r[1] = r[2] = r[3] = 0.f;
        int gm = m0 + (tid >> 2);
        if (gm >= M) return;
        int gk = k0 + (tid & 3) * 4;
        const float* p = A + (long)gm * lda + gk;
        if (gk + 3 < kEnd) {
            float4 v = *(const float4*)p;
            r[0] = v.x; r[1] = v.y; r[2] = v.z; r[3] = v.w;
        } else {
            #pragma unroll
            for (int j = 0; j < 4; ++j) if (gk + j < kEnd) r[j] = p[j];
        }
    };
    auto loadB = [&](int k0, float r[4]) {
        r[0] = r[1] = r[2] = r[3] = 0.f;
        int gk = k0 + (tid >> 4);
        if (gk >= kEnd) return;
        int gn = n0 + (tid & 15) * 4;
        const float* p = B + (long)gk * ldb + gn;
        float4 v = *(const float4*)p;
        r[0] = v.x; r[1] = v.y; r[2] = v.z; r[3] = v.w;
    };
    if (kBeg < kEnd)
        gemm64<false>(kBeg, kEnd, tid, as, bs, acc, loadA, loadB);

    float* C = P + (long)sk * slice;
    const int tx = tid & 15, ty = tid >> 4;
    #pragma unroll
    for (int r = 0; r < 4; ++r) {
        int m = m0 + ty * 4 + r;
        if (m >= M) continue;
        *(float4*)&C[(long)m * ldc + n0 + tx * 4] =
            make_float4(acc[r][0], acc[r][1], acc[r][2], acc[r][3]);
    }
}

// ---------------------------------------------------------------------------
// Slice reduce: out[i] = sum_sk P[sk][i] (+ bias[i % N]). float4/thread.
// ---------------------------------------------------------------------------
__global__ __launch_bounds__(256) void reduce_kernel(
    const float* __restrict__ P, long slice, int skN,
    const float* __restrict__ bias, float* __restrict__ out,
    int total, int N)
{
    int idx = (blockIdx.x * 256 + threadIdx.x) * 4;
    if (idx >= total) return;
    float4 s = *(const float4*)(P + idx);
    for (int k = 1; k < skN; ++k) {
        float4 p = *(const float4*)(P + (long)k * slice + idx);
        s.x += p.x; s.y += p.y; s.z += p.z; s.w += p.w;
    }
    if (bias) {
        const float4 b = *(const float4*)(bias + (idx % N));
        s.x += b.x; s.y += b.y; s.z += b.z; s.w += b.w;
    }
    *(float4*)(out + idx) = s;
}

// ---------------------------------------------------------------------------
// Flash attention (layer 1): grid (13 q-tiles of 32, 8 heads), 256 thr.
// Per chunk of 64 keys: stage K^T,V in LDS; 32x64 scores by outer product;
// CPB bias interp; online softmax; PV accumulate. O -> dense att[401][512].
// ---------------------------------------------------------------------------
__global__ __launch_bounds__(256) void flash_kernel(
    const float* __restrict__ qkv,
    const int* __restrict__ pm, const float* __restrict__ pf,
    const float* __restrict__ T, float* __restrict__ att)
{
    __shared__ float qsT[64 * 32];   // [d][i]
    __shared__ float kT[64 * 68];    // [d][j]
    __shared__ float vs[64 * 68];    // [j][d]
    __shared__ float psT[64 * 34];   // [j][i]
    const int tid = threadIdx.x;
    const int m0 = blockIdx.x * 32, h = blockIdx.y;
    const int tx = tid & 15, ty = tid >> 4;
    const int i0 = ty * 2;

    // stage Q tile transposed (once)
    {
        int i = tid >> 3, dq = (tid & 7) * 8;
        int gm = m0 + i;
        float4 a = make_float4(0, 0, 0, 0), b = make_float4(0, 0, 0, 0);
        if (gm <= 400) {
            const float* p = qkv + (long)gm * 1536 + h * 64 + dq;
            a = *(const float4*)p;
            b = *(const float4*)(p + 4);
        }
        qsT[(dq + 0) * 32 + i] = a.x;
        qsT[(dq + 1) * 32 + i] = a.y;
        qsT[(dq + 2) * 32 + i] = a.z;
        qsT[(dq + 3) * 32 + i] = a.w;
        qsT[(dq + 4) * 32 + i] = b.x;
        qsT[(dq + 5) * 32 + i] = b.y;
        qsT[(dq + 6) * 32 + i] = b.z;
        qsT[(dq + 7) * 32 + i] = b.w;
    }

    float O[2][4] = {{0.f,0.f,0.f,0.f},{0.f,0.f,0.f,0.f}};
    float mr[2] = {-INFINITY, -INFINITY};
    float lr[2] = {0.f, 0.f};
    const float* Tt = T + (long)h * TSTRIDE;
    const int ig0 = (m0 + i0     <= 400) ? m0 + i0     : 400;
    const int ig1 = (m0 + i0 + 1 <= 400) ? m0 + i0 + 1 : 400;

    for (int c = 0; c < 7; ++c) {
        const int kBeg = c * 64;
        __syncthreads();
        {   // stage K^T and V
            int j = tid >> 2, dq = (tid & 3) * 16;
            int gj = kBeg + j;
            float4 k4[4], v4[4];
            #pragma unroll
            for (int q = 0; q < 4; ++q) {
                k4[q] = make_float4(0, 0, 0, 0);
                v4[q] = make_float4(0, 0, 0, 0);
            }
            if (gj <= 400) {
                const float* kp = qkv + (long)gj * 1536 + 512 + h * 64 + dq;
                const float* vp = kp + 512;
                #pragma unroll
                for (int q = 0; q < 4; ++q) {
                    k4[q] = *(const float4*)(kp + q * 4);
                    v4[q] = *(const float4*)(vp + q * 4);
                }
            }
            #pragma unroll
            for (int q = 0; q < 4; ++q) {
                kT[(dq + q * 4 + 0) * 68 + j] = k4[q].x;
                kT[(dq + q * 4 + 1) * 68 + j] = k4[q].y;
                kT[(dq + q * 4 + 2) * 68 + j] = k4[q].z;
                kT[(dq + q * 4 + 3) * 68 + j] = k4[q].w;
                *(float4*)&vs[j * 68 + dq + q * 4] = v4[q];
            }
        }
        __syncthreads();

        float s0[4] = {0.f,0.f,0.f,0.f}, s1[4] = {0.f,0.f,0.f,0.f};
        #pragma unroll
        for (int d = 0; d < 64; ++d) {
            float2 q2 = *(const float2*)&qsT[d * 32 + i0];
            float4 k4 = *(const float4*)&kT[d * 68 + tx * 4];
            s0[0] = fmaf(q2.x, k4.x, s0[0]);
            s0[1] = fmaf(q2.x, k4.y, s0[1]);
            s0[2] = fmaf(q2.x, k4.z, s0[2]);
            s0[3] = fmaf(q2.x, k4.w, s0[3]);
            s1[0] = fmaf(q2.y, k4.x, s1[0]);
            s1[1] = fmaf(q2.y, k4.y, s1[1]);
            s1[2] = fmaf(q2.y, k4.z, s1[2]);
            s1[3] = fmaf(q2.y, k4.w, s1[3]);
        }
        #pragma unroll
        for (int cc = 0; cc < 4; ++cc) {
            int jg = kBeg + tx * 4 + cc;
            if (jg <= 400) {
                int id0 = ig0 * 416 + jg, id1 = ig1 * 416 + jg;
                int ma = pm[id0], mb = pm[id1];
                float fa = pf[id0], fb = pf[id1];
                float a0 = Tt[ma], a1 = Tt[ma + 1];
                float b0 = Tt[mb], b1 = Tt[mb + 1];
                s0[cc] = fmaf(s0[cc], ATT_SCALE, fmaf(fa, a1 - a0, a0));
                s1[cc] = fmaf(s1[cc], ATT_SCALE, fmaf(fb, b1 - b0, b0));
            } else {
                s0[cc] = -INFINITY;
                s1[cc] = -INFINITY;
            }
        }
        #pragma unroll
        for (int r = 0; r < 2; ++r) {
            float* s = r ? s1 : s0;
            float cmax = fmaxf(fmaxf(s[0], s[1]), fmaxf(s[2], s[3]));
            cmax = fmaxf(cmax, __shfl_xor(cmax, 1));
            cmax = fmaxf(cmax, __shfl_xor(cmax, 2));
            cmax = fmaxf(cmax, __shfl_xor(cmax, 4));
            cmax = fmaxf(cmax, __shfl_xor(cmax, 8));
            float mn = fmaxf(mr[r], cmax);
            float al = __expf(mr[r] - mn);
            float rs = 0.f;
            #pragma unroll
            for (int cc = 0; cc < 4; ++cc) {
                float e = __expf(s[cc] - mn);
                s[cc] = e;
                rs += e;
            }
            rs += __shfl_xor(rs, 1);
            rs += __shfl_xor(rs, 2);
            rs += __shfl_xor(rs, 4);
            rs += __shfl_xor(rs, 8);
            lr[r] = lr[r] * al + rs;
            mr[r] = mn;
            #pragma unroll
            for (int cc = 0; cc < 4; ++cc) {
                O[r][cc] *= al;
                psT[(tx * 4 + cc) * 34 + i0 + r] = s[cc];
            }
        }
        __syncthreads();

        #pragma unroll 4
        for (int j = 0; j < 64; ++j) {
            float2 p2 = *(const float2*)&psT[j * 34 + i0];
            float4 v4 = *(const float4*)&vs[j * 68 + tx * 4];
            O[0][0] = fmaf(p2.x, v4.x, O[0][0]);
            O[0][1] = fmaf(p2.x, v4.y, O[0][1]);
            O[0][2] = fmaf(p2.x, v4.z, O[0][2]);
            O[0][3] = fmaf(p2.x, v4.w, O[0][3]);
            O[1][0] = fmaf(p2.y, v4.x, O[1][0]);
            O[1][1] = fmaf(p2.y, v4.y, O[1][1]);
            O[1][2] = fmaf(p2.y, v4.z, O[1][2]);
            O[1][3] = fmaf(p2.y, v4.w, O[1][3]);
        }
    }

    #pragma unroll
    for (int r = 0; r < 2; ++r) {
        int ig = m0 + i0 + r;
        if (ig > 400) continue;
        float inv = 1.f / lr[r];
        *(float4*)&att[(long)ig * 512 + h * 64 + tx * 4] =
            make_float4(O[r][0] * inv, O[r][1] * inv,
                        O[r][2] * inv, O[r][3] * inv);
    }
}

// ---------------------------------------------------------------------------
// proj (layer 1), split-K8, dense att. grid (7,8,8).
// ---------------------------------------------------------------------------
__global__ __launch_bounds__(256) void proj_kernel(
    const float* __restrict__ att, const float* __restrict__ projw,
    float* __restrict__ Pp)
{
    __shared__ float as[16][68], bs[16][68];
    const int tid = threadIdx.x;
    const int m0 = blockIdx.x * 64, n0 = blockIdx.y * 64, sk = blockIdx.z;
    const int kBeg = sk * 64, kEnd = kBeg + 64;
    float acc[4][4] = {};

    auto loadA = [&](int k0, float r[4]) {
        r[0] = r[1] = r[2] = r[3] = 0.f;
        int gm = m0 + (tid >> 2);
        if (gm > 400) return;
        int gk = k0 + (tid & 3) * 4;
        float4 v = *(const float4*)(att + (long)gm * 512 + gk);
        r[0]=v.x; r[1]=v.y; r[2]=v.z; r[3]=v.w;
    };
    auto loadB = [&](int k0, float r[4]) {
        int gk = k0 + (tid >> 4);
        int gn = n0 + (tid & 15) * 4;
        float4 v = *(const float4*)(projw + (long)gk * 512 + gn);
        r[0]=v.x; r[1]=v.y; r[2]=v.z; r[3]=v.w;
    };
    gemm64<false>(kBeg, kEnd, tid, as, bs, acc, loadA, loadB);

    float* C = Pp + (long)sk * PVS;
    const int tx = tid & 15, ty = tid >> 4;
    #pragma unroll
    for (int r = 0; r < 4; ++r) {
        int m = m0 + ty * 4 + r;
        if (m > 400) continue;
        *(float4*)&C[(long)m * 512 + n0 + tx * 4] =
            make_float4(acc[r][0], acc[r][1], acc[r][2], acc[r][3]);
    }
}

// ---------------------------------------------------------------------------
// Per-row split-K reduce + epilogue + LayerNorm. grid 401.
// ---------------------------------------------------------------------------
__global__ __launch_bounds__(256) void rowfuse_kernel(
    const float* __restrict__ P, long slice, int skN, int rowOff,
    const float* __restrict__ bias, int doRelu,
    const float* __restrict__ resid, const float* __restrict__ cls,
    float* __restrict__ h0,
    const float* __restrict__ g, const float* __restrict__ b,
    float* __restrict__ xln)
{
    const int r = blockIdx.x, t = threadIdx.x;
    float v0, v1;
    if (cls && r == 0) {
        v0 = cls[t]; v1 = cls[t + 256];
    } else {
        const float* p = P + (long)(r - rowOff) * DIM;
        v0 = bias[t]; v1 = bias[t + 256];
        for (int k = 0; k < skN; ++k) {
            v0 += p[(long)k * slice + t];
            v1 += p[(long)k * slice + t + 256];
        }
        if (resid) {
            v0 += resid[(long)r * DIM + t];
            v1 += resid[(long)r * DIM + t + 256];
        }
        if (doRelu) { v0 = fmaxf(v0, 0.f); v1 = fmaxf(v1, 0.f); }
    }
    h0[(long)r * DIM + t] = v0;
    h0[(long)r * DIM + t + 256] = v1;

    float s = v0 + v1, sq = v0 * v0 + v1 * v1;
    #pragma unroll
    for (int off = 32; off > 0; off >>= 1) {
        s += __shfl_down(s, off);
        sq += __shfl_down(sq, off);
    }
    __shared__ float ps[4], pq[4];
    int w = t >> 6, lane = t & 63;
    if (lane == 0) { ps[w] = s; pq[w] = sq; }
    __syncthreads();
    float Sm = ps[0] + ps[1] + ps[2] + ps[3];
    float Q = pq[0] + pq[1] + pq[2] + pq[3];
    float mean = Sm * (1.f / DIM);
    float var = Q * (1.f / DIM) - mean * mean;
    float inv = rsqrtf(var + LN_EPS);
    xln[(long)r * DIM + t]       = (v0 - mean) * inv * g[t] + b[t];
    xln[(long)r * DIM + t + 256] = (v1 - mean) * inv * g[t + 256] + b[t + 256];
}

// ---------------------------------------------------------------------------
// CLS flash-decode (layer 2): grid (8 heads, 7 key-chunks). Dense qkv.
// ---------------------------------------------------------------------------
__global__ __launch_bounds__(256) void cls_decode_kernel(
    const float* __restrict__ qkv,
    const int* __restrict__ pm, const float* __restrict__ pf,
    const float* __restrict__ T,
    float* __restrict__ cms, float* __restrict__ cpv)
{
    const int h = blockIdx.x, c = blockIdx.y, tid = threadIdx.x;
    const int kBeg = c * 64;
    __shared__ float q0[64], scraw[64], p[64], red[4][64], rr[2];

    if (tid < 64) q0[tid] = qkv[h * 64 + tid];
    __syncthreads();

    {
        int k = tid >> 2, q = tid & 3;
        int j = kBeg + k;
        float dot = 0.f;
        if (j < NP) {
            const float* kp = qkv + (long)j * 1536 + 512 + h * 64 + q * 16;
            const float* qp = q0 + q * 16;
            #pragma unroll
            for (int d = 0; d < 16; d += 4) {
                float4 kv = *(const float4*)(kp + d);
                float4 qq = *(const float4*)(qp + d);
                dot = fmaf(qq.x, kv.x, dot);
                dot = fmaf(qq.y, kv.y, dot);
                dot = fmaf(qq.z, kv.z, dot);
                dot = fmaf(qq.w, kv.w, dot);
            }
        }
        dot += __shfl_down(dot, 2);
        dot += __shfl_down(dot, 1);
        if (q == 0) scraw[k] = dot;
    }
    __syncthreads();

    if (tid < 64) {
        int j = kBeg + tid;
        float s;
        if (j < NP) {
            int mm = pm[j];
            float fr = pf[j];
            const float* Tt = T + (long)h * TSTRIDE;
            float t0 = Tt[mm], t1 = Tt[mm + 1];
            s = fmaf(scraw[tid], ATT_SCALE, fmaf(fr, t1 - t0, t0));
        } else {
            s = -INFINITY;
        }
        float m = s;
        #pragma unroll
        for (int off = 32; off > 0; off >>= 1)
            m = fmaxf(m, __shfl_xor(m, off));
        float e = (j < NP) ? __expf(s - m) : 0.f;
        float sum = e;
        #pragma unroll
        for (int off = 32; off > 0; off >>= 1)
            sum += __shfl_xor(sum, off);
        p[tid] = e;
        if (tid == 0) { rr[0] = m; rr[1] = sum; }
    }
    __syncthreads();

    {
        int w = tid >> 6, d = tid & 63;
        float acc = 0.f;
        for (int k = w; k < 64; k += 4) {
            int j = kBeg + k;
            if (j >= NP) break;
            acc = fmaf(p[k], qkv[(long)j * 1536 + 1024 + h * 64 + d], acc);
        }
        red[w][d] = acc;
    }
    __syncthreads();
    if (tid < 64) {
        cpv[((long)h * 7 + c) * 64 + tid] =
            red[0][tid] + red[1][tid] + red[2][tid] + red[3][tid];
        if (tid == 0) {
            cms[(h * 7 + c) * 2 + 0] = rr[0];
            cms[(h * 7 + c) * 2 + 1] = rr[1];
        }
    }
}

// CLS proj with inlined LSE combine. grid 8 x 256 thr.
__global__ __launch_bounds__(256) void cls_proj_kernel(
    const float* __restrict__ cms, const float* __restrict__ cpv,
    const float* __restrict__ projw, const float* __restrict__ projb,
    float* __restrict__ proj0)
{
    __shared__ float av[512], red[4][64];
    const int b = blockIdx.x, tid = threadIdx.x;
    for (int d = tid; d < 512; d += 256) {
        int h = d >> 6, dd = d & 63;
        float M = -INFINITY;
        #pragma unroll
        for (int c = 0; c < 7; ++c)
            M = fmaxf(M, cms[(h * 7 + c) * 2]);
        float S = 0.f, acc = 0.f;
        #pragma unroll
        for (int c = 0; c < 7; ++c) {
            float e = __expf(cms[(h * 7 + c) * 2] - M);
            S += cms[(h * 7 + c) * 2 + 1] * e;
            acc += cpv[((long)h * 7 + c) * 64 + dd] * e;
        }
        av[d] = acc / S;
    }
    __syncthreads();
    int g = tid >> 6, n = b * 64 + (tid & 63);
    float acc = 0.f;
    for (int k = g * 128; k < g * 128 + 128; ++k)
        acc = fmaf(av[k], projw[(long)k * 512 + n], acc);
    red[g][tid & 63] = acc;
    __syncthreads();
    if (tid < 64)
        proj0[b * 64 + tid] = red[0][tid] + red[1][tid] + red[2][tid]
                              + red[3][tid] + projb[b * 64 + tid];
}

// CLS out: h1[0] + proj0 -> LN -> fc2 -> out[2]. grid 1.
__global__ __launch_bounds__(256) void cls_out_kernel(
    const float* __restrict__ h0, const float* __restrict__ proj0,
    const float* __restrict__ g, const float* __restrict__ b,
    const float* __restrict__ fc2w, const float* __restrict__ fc2b,
    float* __restrict__ out)
{
    const int t = threadIdx.x;
    float v0 = h0[t] + proj0[t];
    float v1 = h0[t + 256] + proj0[t + 256];
    float s = v0 + v1, sq = v0 * v0 + v1 * v1;
    #pragma unroll
    for (int off = 32; off > 0; off >>= 1) {
        s += __shfl_down(s, off);
        sq += __shfl_down(sq, off);
    }
    __shared__ float ps[4], pq[4], pc0[4], pc1[4];
    int w = t >> 6, lane = t & 63;
    if (lane == 0) { ps[w] = s; pq[w] = sq; }
    __syncthreads();
    float Sm = ps[0] + ps[1] + ps[2] + ps[3];
    float Q = pq[0] + pq[1] + pq[2] + pq[3];
    float mean = Sm * (1.f / DIM);
    float var = Q * (1.f / DIM) - mean * mean;
    float inv = rsqrtf(var + LN_EPS);
    float n0 = (v0 - mean) * inv * g[t] + b[t];
    float n1 = (v1 - mean) * inv * g[t + 256] + b[t + 256];
    float c0 = n0 * fc2w[t * 2]     + n1 * fc2w[(t + 256) * 2];
    float c1 = n0 * fc2w[t * 2 + 1] + n1 * fc2w[(t + 256) * 2 + 1];
    #pragma unroll
    for (int off = 32; off > 0; off >>= 1) {
        c0 += __shfl_down(c0, off);
        c1 += __shfl_down(c1, off);
    }
    if (lane == 0) { pc0[w] = c0; pc1[w] = c1; }
    __syncthreads();
    if (t == 0) {
        out[0] = pc0[0] + pc0[1] + pc0[2] + pc0[3] + fc2b[0];
        out[1] = pc1[0] + pc1[1] + pc1[2] + pc1[3] + fc2b[1];
    }
}

// ---------------------------------------------------------------------------
// Mega init: [0,896) fc1 split-K16 -> Pp; [896,1410) CPB angle tables;
// [1410,2039) pair -> (angle idx, frac).
// ---------------------------------------------------------------------------
__global__ __launch_bounds__(256) void mega_kernel(
    const float* __restrict__ hin, const float* __restrict__ fc1_w,
    const float* __restrict__ w1_0, const float* __restrict__ b1_0,
    const float* __restrict__ w2_0, const float* __restrict__ b2_0,
    const float* __restrict__ w1_1, const float* __restrict__ b1_1,
    const float* __restrict__ w2_1, const float* __restrict__ b2_1,
    const float* __restrict__ coords,
    float* __restrict__ Pp, float* __restrict__ T,
    int* __restrict__ pm, float* __restrict__ pf)
{
    __shared__ float smem[2176];
    float (*as)[68] = (float(*)[68])smem;
    float (*bs)[68] = (float(*)[68])(smem + 1088);
    float (*red)[64][8] = (float(*)[64][8])smem;
    const int bid = blockIdx.x, tid = threadIdx.x;

    if (bid < 896) {
        int sk = bid / 56, rem = bid % 56;
        int m0 = (rem % 7) * 64, n0 = (rem / 7) * 64;
        int kBeg = sk * 64, kEnd = kBeg + 64;
        float acc[4][4] = {};
        auto loadA = [&](int k0, float r[4]) {
            r[0]=r[1]=r[2]=r[3]=0.f;
            int gm = m0 + (tid >> 2);
            if (gm >= 400) return;
            int gk = k0 + (tid & 3) * 4;
            float4 v = *(const float4*)(hin + (long)gm * 1024 + gk);
            r[0]=v.x; r[1]=v.y; r[2]=v.z; r[3]=v.w;
        };
        auto loadB = [&](int k0, float r[4]) {
            int gk = k0 + (tid >> 4);
            int gn = n0 + (tid & 15) * 4;
            float4 v = *(const float4*)(fc1_w + (long)gk * 512 + gn);
            r[0]=v.x; r[1]=v.y; r[2]=v.z; r[3]=v.w;
        };
        gemm64<false>(kBeg, kEnd, tid, as, bs, acc, loadA, loadB);
        float* C = Pp + (long)sk * PVS;
        const int tx = tid & 15, ty = tid >> 4;
        #pragma unroll
        for (int r = 0; r < 4; ++r) {
            int m = m0 + ty * 4 + r;
            if (m >= 400) continue;
            *(float4*)&C[(long)m * 512 + n0 + tx * 4] =
                make_float4(acc[r][0], acc[r][1], acc[r][2], acc[r][3]);
        }
    } else if (bid < 1410) {
        int tb = bid - 896;
        int z = tb / 257, ab = tb % 257;
        const float* w1 = z ? w1_1 : w1_0;
        const float* b1 = z ? b1_1 : b1_0;
        const float* w2 = z ? w2_1 : w2_0;
        const float* b2 = z ? b2_1 : b2_0;
        const int lane = tid & 63, wv = tid >> 6;
        float ca = 0.f, sa = 0.f;
        if (ab != 256) {
            float th = fmaf((float)(ab * 64 + lane),
                            (float)(2.0 * M_PI / CPB_M), -(float)M_PI);
            sincosf(th, &sa, &ca);
        } else if (lane == 0) {
            sincosf((float)M_PI, &sa, &ca);  // wrap row; lanes>0 zero-vec
        }
        float a8[8] = {};
        const int kbeg = wv * 128;
        #pragma unroll 4
        for (int k = kbeg; k < kbeg + 128; ++k) {
            float hk = fmaxf(fmaf(ca, w1[k],
                                  fmaf(sa, w1[512 + k], b1[k])), 0.f);
            #pragma unroll
            for (int h2 = 0; h2 < 8; ++h2)
                a8[h2] = fmaf(hk, w2[k * 8 + h2], a8[h2]);
        }
        #pragma unroll
        for (int h2 = 0; h2 < 8; ++h2) red[wv][lane][h2] = a8[h2];
        __syncthreads();
        if (tid < 64) {
            int aidx = ab * 64 + tid;
            #pragma unroll
            for (int h2 = 0; h2 < 8; ++h2)
                T[(long)(z * 8 + h2) * TSTRIDE + aidx] =
                    red[0][tid][h2] + red[1][tid][h2] +
                    red[2][tid][h2] + red[3][tid][h2] + b2[h2];
        }
    } else {
        int p = (bid - 1410) * 256 + tid;
        if (p < NP * NP) {
            int i = p / NP, j = p - i * NP;
            float xi = (i == 0) ? 0.f : coords[(i - 1) * 2];
            float yi = (i == 0) ? 0.f : coords[(i - 1) * 2 + 1];
            float xj = (j == 0) ? 0.f : coords[(j - 1) * 2];
            float yj = (j == 0) ? 0.f : coords[(j - 1) * 2 + 1];
            float rx = xi - xj, ry = yi - yj;
            int mm; float fr;
            if (rx == 0.f && ry == 0.f) {
                mm = CPB_M + 1; fr = 0.f;
            } else {
                float x = (atan2f(ry, rx) + 3.14159265358979f)
                          * (float)(CPB_M / (2.0 * M_PI));
                int mi = (int)x;
                fr = x - (float)mi;
                mm = (mi >= CPB_M) ? mi - CPB_M : mi;
            }
            pm[i * 416 + j] = mm;
            pf[i * 416 + j] = fr;
        }
    }
}

// ---------------------------------------------------------------------------
extern "C" void kernel_launch(void* const* d_in, const int* in_sizes, int n_in,
                              void* d_out, int out_size, void* d_ws, size_t ws_size,
                              hipStream_t stream)
{
    const float* coords = (const float*)d_in[1];
    float* ws = (float*)d_ws;
    float* h0   = ws;                    ws += 401L * 512;
    float* xln  = ws;                    ws += 401L * 512;
    float* T    = ws;                    ws += 16L * TSTRIDE;
    int*   pm   = (int*)ws;              ws += 401L * 416;
    float* pf   = ws;                    ws += 401L * 416;
    float* Pq   = ws;                    ws += 4L * PQS;
    float* qkv  = ws;                    ws += 401L * 1536;
    float* att  = ws;                    ws += 401L * 512;
    float* Pp   = ws;                    ws += 16L * PVS;
    float* proj0 = ws;                   ws += 512;
    float* cms  = ws;                    ws += 8L * 7 * 2;
    float* cpv  = ws;                    ws += 8L * 7 * 64;

    // phase 0: fc1 (K16) + both CPB angle tables + pair->angle map
    mega_kernel<<<2039, 256, 0, stream>>>(
        (const float*)d_in[0], (const float*)d_in[2],
        (const float*)d_in[7],  (const float*)d_in[8],
        (const float*)d_in[9],  (const float*)d_in[10],
        (const float*)d_in[17], (const float*)d_in[18],
        (const float*)d_in[19], (const float*)d_in[20],
        coords, Pp, T, pm, pf);

    // fc1 reduce + relu + cls + LN(l1) -> h0, xln
    rowfuse_kernel<<<401, 256, 0, stream>>>(
        Pp, PVS, 16, 1, (const float*)d_in[3], 1, nullptr,
        (const float*)d_in[4], h0,
        (const float*)d_in[5], (const float*)d_in[6], xln);

    // -------- layer 1 (full attention, flash) --------
    gemm_split_kernel<<<dim3(7, 24, 4), 256, 0, stream>>>(
        xln, 512, (const float*)d_in[11], 1536, Pq, 1536, PQS,
        401, 1536, 512, 4);
    reduce_kernel<<<602, 256, 0, stream>>>(
        Pq, PQS, 4, (const float*)d_in[12], qkv, 401 * 1536, 1536);
    flash_kernel<<<dim3(13, 8), 256, 0, stream>>>(qkv, pm, pf, T, att);
    proj_kernel<<<dim3(7, 8, 8), 256, 0, stream>>>(
        att, (const float*)d_in[13], Pp);
    rowfuse_kernel<<<401, 256, 0, stream>>>(
        Pp, PVS, 8, 0, (const float*)d_in[14], 0, h0, nullptr, h0,
        (const float*)d_in[15], (const float*)d_in[16], xln);

    // -------- layer 2 (CLS row only, flash-decode) --------
    gemm_split_kernel<<<dim3(7, 24, 4), 256, 0, stream>>>(
        xln, 512, (const float*)d_in[21], 1536, Pq, 1536, PQS,
        401, 1536, 512, 4);
    reduce_kernel<<<602, 256, 0, stream>>>(
        Pq, PQS, 4, (const float*)d_in[22], qkv, 401 * 1536, 1536);
    cls_decode_kernel<<<dim3(8, 7), 256, 0, stream>>>(
        qkv, pm, pf, T + 8L * TSTRIDE, cms, cpv);
    cls_proj_kernel<<<8, 256, 0, stream>>>(
        cms, cpv, (const float*)d_in[23], (const float*)d_in[24], proj0);
    cls_out_kernel<<<1, 256, 0, stream>>>(
        h0, proj0, (const float*)d_in[25], (const float*)d_in[26],
        (const float*)d_in[27], (const float*)d_in[28], (float*)d_out);
}

// Round 12
// 252.398 us; speedup vs baseline: 2.0370x; 1.1230x over previous
//
#include <hip/hip_runtime.h>
#include <math.h>

#define NP 401            // tokens incl. CLS (400 patches, side=20, add=0)
#define DIM 512
#define LN_EPS 1e-5f
#define ATT_SCALE 0.125f
#define SP 448            // S plane row stride
#define PLANE (NP * SP)
#define CPB_M 16384       // angle-table resolution
#define TSTRIDE (CPB_M + 64)
#define PQS (401L * 1536) // qkv partial slice stride
#define PVS (401L * 512)  // pv / proj partial slice stride

// ---------------------------------------------------------------------------
// 64x64-tile GEMM body: 256 thr, 4x4 micro-tile, K-chunk 16, register
// double-buffered staging via caller-supplied loaders.
// ---------------------------------------------------------------------------
template<bool TB, typename LA, typename LB>
__device__ __forceinline__ void gemm64(
    int kBeg, int kEnd, int tid,
    float (*as)[68], float (*bs)[68], float (&acc)[4][4],
    LA&& loadA, LB&& loadB)
{
    float aR[4], bR[4];
    loadA(kBeg, aR);
    loadB(kBeg, bR);
    for (int k0 = kBeg; k0 < kEnd; k0 += 16) {
        const int arow = tid >> 2, aq = tid & 3;
        as[aq * 4 + 0][arow] = aR[0];
        as[aq * 4 + 1][arow] = aR[1];
        as[aq * 4 + 2][arow] = aR[2];
        as[aq * 4 + 3][arow] = aR[3];
        if (!TB) {
            *(float4*)&bs[tid >> 4][(tid & 15) * 4] =
                make_float4(bR[0], bR[1], bR[2], bR[3]);
        } else {
            bs[aq * 4 + 0][arow] = bR[0];
            bs[aq * 4 + 1][arow] = bR[1];
            bs[aq * 4 + 2][arow] = bR[2];
            bs[aq * 4 + 3][arow] = bR[3];
        }
        __syncthreads();
        float nA[4] = {0.f,0.f,0.f,0.f}, nB[4] = {0.f,0.f,0.f,0.f};
        if (k0 + 16 < kEnd) { loadA(k0 + 16, nA); loadB(k0 + 16, nB); }
        const int tx = tid & 15, ty = tid >> 4;
        #pragma unroll
        for (int kk = 0; kk < 16; ++kk) {
            float4 a4 = *(const float4*)&as[kk][ty * 4];
            float4 b4 = *(const float4*)&bs[kk][tx * 4];
            float av[4] = {a4.x, a4.y, a4.z, a4.w};
            float bv[4] = {b4.x, b4.y, b4.z, b4.w};
            #pragma unroll
            for (int r = 0; r < 4; ++r)
                #pragma unroll
                for (int c = 0; c < 4; ++c)
                    acc[r][c] = fmaf(av[r], bv[c], acc[r][c]);
        }
        __syncthreads();
        #pragma unroll
        for (int j = 0; j < 4; ++j) { aR[j] = nA[j]; bR[j] = nB[j]; }
    }
}

// ---------------------------------------------------------------------------
// Generic split-K GEMM: P[sk] = A[:, slice] @ B[slice, :]  (raw partials)
// ---------------------------------------------------------------------------
__global__ __launch_bounds__(256) void gemm_split_kernel(
    const float* __restrict__ A, int lda,
    const float* __restrict__ B, int ldb,
    float* __restrict__ P, int ldc, long slice,
    int M, int N, int K, int skN)
{
    __shared__ float as[16][68], bs[16][68];
    const int tid = threadIdx.x;
    const int m0 = blockIdx.x * 64, n0 = blockIdx.y * 64;
    const int sk = blockIdx.z;
    const int KS = ((K + skN * 16 - 1) / (skN * 16)) * 16;
    const int kBeg = sk * KS;
    const int kEnd = (kBeg + KS < K) ? kBeg + KS : K;
    float acc[4][4] = {};

    auto loadA = [&](int k0, float r[4]) {
        r[0] = r[1] = r[2] = r[3] = 0.f;
        int gm = m0 + (tid >> 2);
        if (gm >= M) return;
        int gk = k0 + (tid & 3) * 4;
        const float* p = A + (long)gm * lda + gk;
        if (gk + 3 < kEnd) {
            float4 v = *(const float4*)p;
            r[0] = v.x; r[1] = v.y; r[2] = v.z; r[3] = v.w;
        } else {
            #pragma unroll
            for (int j = 0; j < 4; ++j) if (gk + j < kEnd) r[j] = p[j];
        }
    };
    auto loadB = [&](int k0, float r[4]) {
        r[0] = r[1] = r[2] = r[3] = 0.f;
        int gk = k0 + (tid >> 4);
        if (gk >= kEnd) return;
        int gn = n0 + (tid & 15) * 4;
        const float* p = B + (long)gk * ldb + gn;
        float4 v = *(const float4*)p;
        r[0] = v.x; r[1] = v.y; r[2] = v.z; r[3] = v.w;
    };
    if (kBeg < kEnd)
        gemm64<false>(kBeg, kEnd, tid, as, bs, acc, loadA, loadB);

    float* C = P + (long)sk * slice;
    const int tx = tid & 15, ty = tid >> 4;
    #pragma unroll
    for (int r = 0; r < 4; ++r) {
        int m = m0 + ty * 4 + r;
        if (m >= M) continue;
        *(float4*)&C[(long)m * ldc + n0 + tx * 4] =
            make_float4(acc[r][0], acc[r][1], acc[r][2], acc[r][3]);
    }
}

// ---------------------------------------------------------------------------
// Slice reduce: out[i] = sum_sk P[sk][i] (+ bias[i % N]). float4/thread.
// ---------------------------------------------------------------------------
__global__ __launch_bounds__(256) void reduce_kernel(
    const float* __restrict__ P, long slice, int skN,
    const float* __restrict__ bias, float* __restrict__ out,
    int total, int N)
{
    int idx = (blockIdx.x * 256 + threadIdx.x) * 4;
    if (idx >= total) return;
    float4 s = *(const float4*)(P + idx);
    for (int k = 1; k < skN; ++k) {
        float4 p = *(const float4*)(P + (long)k * slice + idx);
        s.x += p.x; s.y += p.y; s.z += p.z; s.w += p.w;
    }
    if (bias) {
        const float4 b = *(const float4*)(bias + (idx % N));
        s.x += b.x; s.y += b.y; s.z += b.z; s.w += b.w;
    }
    *(float4*)(out + idx) = s;
}

// ---------------------------------------------------------------------------
// QK^T (layer 1): dense qkv staging; CPB bias interp epilogue. grid (7,7,8).
// ---------------------------------------------------------------------------
__global__ __launch_bounds__(256) void qk_kernel(
    const float* __restrict__ qkv,
    const int* __restrict__ pm, const float* __restrict__ pf,
    const float* __restrict__ T, float* __restrict__ S)
{
    __shared__ float as[16][68], bs[16][68];
    const int tid = threadIdx.x;
    const int m0 = blockIdx.x * 64, n0 = blockIdx.y * 64, h = blockIdx.z;
    float acc[4][4] = {};

    auto loadQ = [&](int k0, float r[4]) {
        int gm = m0 + (tid >> 2);
        if (gm > 400) { r[0]=r[1]=r[2]=r[3]=0.f; return; }
        int gk = k0 + (tid & 3) * 4;
        float4 v = *(const float4*)(qkv + (long)gm * 1536 + h * 64 + gk);
        r[0]=v.x; r[1]=v.y; r[2]=v.z; r[3]=v.w;
    };
    auto loadK = [&](int k0, float r[4]) {
        int gn = n0 + (tid >> 2);
        if (gn > 400) { r[0]=r[1]=r[2]=r[3]=0.f; return; }
        int gk = k0 + (tid & 3) * 4;
        float4 v = *(const float4*)(qkv + (long)gn * 1536 + 512 + h * 64 + gk);
        r[0]=v.x; r[1]=v.y; r[2]=v.z; r[3]=v.w;
    };
    gemm64<true>(0, 64, tid, as, bs, acc, loadQ, loadK);

    const int tx = tid & 15, ty = tid >> 4;
    const float* Tt = T + (long)h * TSTRIDE;
    float* Sp = S + (long)h * PLANE;
    #pragma unroll
    for (int r = 0; r < 4; ++r) {
        int i = m0 + ty * 4 + r;
        if (i > 400) continue;
        #pragma unroll
        for (int c = 0; c < 4; ++c) {
            int j = n0 + tx * 4 + c;
            if (j > 400) continue;
            int id = i * 416 + j;
            int mm = pm[id];
            float fr = pf[id];
            float t0 = Tt[mm], t1 = Tt[mm + 1];
            Sp[(long)i * SP + j] =
                fmaf(acc[r][c], ATT_SCALE, fmaf(fr, t1 - t0, t0));
        }
    }
}

// ---------------------------------------------------------------------------
// Softmax, wave-per-row. grid 802 x 256 thr (4 rows/block).
// ---------------------------------------------------------------------------
__global__ __launch_bounds__(256) void softmax_kernel(float* __restrict__ S)
{
    int r = blockIdx.x * 4 + (threadIdx.x >> 6);
    if (r >= 3208) return;
    int hh = r / 401, i = r - hh * 401;
    float* row = S + (long)hh * PLANE + (long)i * SP;
    int lane = threadIdx.x & 63;
    float v[7], mx = -INFINITY;
    #pragma unroll
    for (int j = 0; j < 7; ++j) {
        int c = lane + j * 64;
        v[j] = (c < NP) ? row[c] : -INFINITY;
        mx = fmaxf(mx, v[j]);
    }
    #pragma unroll
    for (int off = 32; off > 0; off >>= 1)
        mx = fmaxf(mx, __shfl_xor(mx, off));
    float s = 0.f;
    #pragma unroll
    for (int j = 0; j < 7; ++j) {
        v[j] = (lane + j * 64 < NP) ? __expf(v[j] - mx) : 0.f;
        s += v[j];
    }
    #pragma unroll
    for (int off = 32; off > 0; off >>= 1)
        s += __shfl_xor(s, off);
    float inv = 1.f / s;
    #pragma unroll
    for (int j = 0; j < 7; ++j) {
        int c = lane + j * 64;
        if (c < NP) row[c] = v[j] * inv;
    }
}

// ---------------------------------------------------------------------------
// PV (layer 1), split-K4 over keys, dense V. grid (7,1,32): z = h*4 + sk.
// ---------------------------------------------------------------------------
__global__ __launch_bounds__(256) void pv_kernel(
    const float* __restrict__ S, const float* __restrict__ qkv,
    float* __restrict__ Pv)
{
    __shared__ float as[16][68], bs[16][68];
    const int tid = threadIdx.x;
    const int m0 = blockIdx.x * 64;
    const int h = blockIdx.z >> 2, sk = blockIdx.z & 3;
    const int kBeg = sk * 112;
    const int kEnd = (kBeg + 112 < NP) ? kBeg + 112 : NP;
    float acc[4][4] = {};

    auto loadA = [&](int k0, float r[4]) {
        r[0] = r[1] = r[2] = r[3] = 0.f;
        int gm = m0 + (tid >> 2);
        if (gm > 400) return;
        int gk = k0 + (tid & 3) * 4;
        const float* p = S + (long)h * PLANE + (long)gm * SP + gk;
        if (gk + 3 < kEnd) {
            float4 v = *(const float4*)p;
            r[0]=v.x; r[1]=v.y; r[2]=v.z; r[3]=v.w;
        } else {
            #pragma unroll
            for (int j = 0; j < 4; ++j) if (gk + j < kEnd) r[j] = p[j];
        }
    };
    auto loadB = [&](int k0, float r[4]) {
        r[0] = r[1] = r[2] = r[3] = 0.f;
        int key = k0 + (tid >> 4);
        if (key >= kEnd) return;
        int d = (tid & 15) * 4;
        float4 v = *(const float4*)(qkv + (long)key * 1536 + 1024 + h * 64 + d);
        r[0]=v.x; r[1]=v.y; r[2]=v.z; r[3]=v.w;
    };
    gemm64<false>(kBeg, kEnd, tid, as, bs, acc, loadA, loadB);

    float* C = Pv + (long)sk * PVS;
    const int tx = tid & 15, ty = tid >> 4;
    #pragma unroll
    for (int r = 0; r < 4; ++r) {
        int m = m0 + ty * 4 + r;
        if (m > 400) continue;
        *(float4*)&C[(long)m * 512 + h * 64 + tx * 4] =
            make_float4(acc[r][0], acc[r][1], acc[r][2], acc[r][3]);
    }
}

// ---------------------------------------------------------------------------
// proj (layer 1), split-K8, dense att. grid (7,8,8).
// ---------------------------------------------------------------------------
__global__ __launch_bounds__(256) void proj_kernel(
    const float* __restrict__ att, const float* __restrict__ projw,
    float* __restrict__ Pp)
{
    __shared__ float as[16][68], bs[16][68];
    const int tid = threadIdx.x;
    const int m0 = blockIdx.x * 64, n0 = blockIdx.y * 64, sk = blockIdx.z;
    const int kBeg = sk * 64, kEnd = kBeg + 64;
    float acc[4][4] = {};

    auto loadA = [&](int k0, float r[4]) {
        r[0] = r[1] = r[2] = r[3] = 0.f;
        int gm = m0 + (tid >> 2);
        if (gm > 400) return;
        int gk = k0 + (tid & 3) * 4;
        float4 v = *(const float4*)(att + (long)gm * 512 + gk);
        r[0]=v.x; r[1]=v.y; r[2]=v.z; r[3]=v.w;
    };
    auto loadB = [&](int k0, float r[4]) {
        int gk = k0 + (tid >> 4);
        int gn = n0 + (tid & 15) * 4;
        float4 v = *(const float4*)(projw + (long)gk * 512 + gn);
        r[0]=v.x; r[1]=v.y; r[2]=v.z; r[3]=v.w;
    };
    gemm64<false>(kBeg, kEnd, tid, as, bs, acc, loadA, loadB);

    float* C = Pp + (long)sk * PVS;
    const int tx = tid & 15, ty = tid >> 4;
    #pragma unroll
    for (int r = 0; r < 4; ++r) {
        int m = m0 + ty * 4 + r;
        if (m > 400) continue;
        *(float4*)&C[(long)m * 512 + n0 + tx * 4] =
            make_float4(acc[r][0], acc[r][1], acc[r][2], acc[r][3]);
    }
}

// ---------------------------------------------------------------------------
// Per-row split-K reduce + epilogue + LayerNorm. grid 401.
// ---------------------------------------------------------------------------
__global__ __launch_bounds__(256) void rowfuse_kernel(
    const float* __restrict__ P, long slice, int skN, int rowOff,
    const float* __restrict__ bias, int doRelu,
    const float* __restrict__ resid, const float* __restrict__ cls,
    float* __restrict__ h0,
    const float* __restrict__ g, const float* __restrict__ b,
    float* __restrict__ xln)
{
    const int r = blockIdx.x, t = threadIdx.x;
    float v0, v1;
    if (cls && r == 0) {
        v0 = cls[t]; v1 = cls[t + 256];
    } else {
        const float* p = P + (long)(r - rowOff) * DIM;
        v0 = bias[t]; v1 = bias[t + 256];
        for (int k = 0; k < skN; ++k) {
            v0 += p[(long)k * slice + t];
            v1 += p[(long)k * slice + t + 256];
        }
        if (resid) {
            v0 += resid[(long)r * DIM + t];
            v1 += resid[(long)r * DIM + t + 256];
        }
        if (doRelu) { v0 = fmaxf(v0, 0.f); v1 = fmaxf(v1, 0.f); }
    }
    h0[(long)r * DIM + t] = v0;
    h0[(long)r * DIM + t + 256] = v1;

    float s = v0 + v1, sq = v0 * v0 + v1 * v1;
    #pragma unroll
    for (int off = 32; off > 0; off >>= 1) {
        s += __shfl_down(s, off);
        sq += __shfl_down(sq, off);
    }
    __shared__ float ps[4], pq[4];
    int w = t >> 6, lane = t & 63;
    if (lane == 0) { ps[w] = s; pq[w] = sq; }
    __syncthreads();
    float Sm = ps[0] + ps[1] + ps[2] + ps[3];
    float Q = pq[0] + pq[1] + pq[2] + pq[3];
    float mean = Sm * (1.f / DIM);
    float var = Q * (1.f / DIM) - mean * mean;
    float inv = rsqrtf(var + LN_EPS);
    xln[(long)r * DIM + t]       = (v0 - mean) * inv * g[t] + b[t];
    xln[(long)r * DIM + t + 256] = (v1 - mean) * inv * g[t + 256] + b[t + 256];
}

// ---------------------------------------------------------------------------
// CLS flash-decode (layer 2): grid (8 heads, 7 key-chunks of 64).
// Reads the 4 qkv split-K partial slices + bias INLINE (each element is
// consumed exactly once here, so no dense qkv / reduce pass is needed).
// ---------------------------------------------------------------------------
__global__ __launch_bounds__(256) void cls_decode_kernel(
    const float* __restrict__ Pq, const float* __restrict__ qkvb,
    const int* __restrict__ pm, const float* __restrict__ pf,
    const float* __restrict__ T,
    float* __restrict__ cms, float* __restrict__ cpv)
{
    const int h = blockIdx.x, c = blockIdx.y, tid = threadIdx.x;
    const int kBeg = c * 64;
    __shared__ float q0[64], scraw[64], p[64], red[4][64], rr[2];

    if (tid < 64) {
        long o = h * 64 + tid;
        q0[tid] = Pq[o] + Pq[PQS + o] + Pq[2 * PQS + o] + Pq[3 * PQS + o]
                  + qkvb[o];
    }
    __syncthreads();

    // scores: key k = tid>>2 (4 lanes/key, 16 dims each), shuffle-reduce
    {
        int k = tid >> 2, q = tid & 3;
        int j = kBeg + k;
        float dot = 0.f;
        if (j < NP) {
            long base = (long)j * 1536 + 512 + h * 64 + q * 16;
            #pragma unroll
            for (int d = 0; d < 16; d += 4) {
                float4 x0 = *(const float4*)(Pq + base + d);
                float4 x1 = *(const float4*)(Pq + PQS + base + d);
                float4 x2 = *(const float4*)(Pq + 2 * PQS + base + d);
                float4 x3 = *(const float4*)(Pq + 3 * PQS + base + d);
                float4 bb = *(const float4*)(qkvb + 512 + h * 64 + q * 16 + d);
                float4 qq = *(const float4*)(q0 + q * 16 + d);
                dot = fmaf(qq.x, x0.x + x1.x + x2.x + x3.x + bb.x, dot);
                dot = fmaf(qq.y, x0.y + x1.y + x2.y + x3.y + bb.y, dot);
                dot = fmaf(qq.z, x0.z + x1.z + x2.z + x3.z + bb.z, dot);
                dot = fmaf(qq.w, x0.w + x1.w + x2.w + x3.w + bb.w, dot);
            }
        }
        dot += __shfl_down(dot, 2);
        dot += __shfl_down(dot, 1);
        if (q == 0) scraw[k] = dot;
    }
    __syncthreads();

    // bias + local softmax on wave 0
    if (tid < 64) {
        int j = kBeg + tid;
        float s;
        if (j < NP) {
            int mm = pm[j];                   // row 0 of pair map
            float fr = pf[j];
            const float* Tt = T + (long)h * TSTRIDE;
            float t0 = Tt[mm], t1 = Tt[mm + 1];
            s = fmaf(scraw[tid], ATT_SCALE, fmaf(fr, t1 - t0, t0));
        } else {
            s = -INFINITY;
        }
        float m = s;
        #pragma unroll
        for (int off = 32; off > 0; off >>= 1)
            m = fmaxf(m, __shfl_xor(m, off));
        float e = (j < NP) ? __expf(s - m) : 0.f;
        float sum = e;
        #pragma unroll
        for (int off = 32; off > 0; off >>= 1)
            sum += __shfl_xor(sum, off);
        p[tid] = e;
        if (tid == 0) { rr[0] = m; rr[1] = sum; }
    }
    __syncthreads();

    // partial PV: d = lane, wave w handles keys k ≡ w (mod 4)
    {
        int w = tid >> 6, d = tid & 63;
        float vb = qkvb[1024 + h * 64 + d];
        float acc = 0.f;
        for (int k = w; k < 64; k += 4) {
            int j = kBeg + k;
            if (j >= NP) break;
            long o = (long)j * 1536 + 1024 + h * 64 + d;
            float v = Pq[o] + Pq[PQS + o] + Pq[2 * PQS + o] + Pq[3 * PQS + o]
                      + vb;
            acc = fmaf(p[k], v, acc);
        }
        red[w][d] = acc;
    }
    __syncthreads();
    if (tid < 64) {
        cpv[((long)h * 7 + c) * 64 + tid] =
            red[0][tid] + red[1][tid] + red[2][tid] + red[3][tid];
        if (tid == 0) {
            cms[(h * 7 + c) * 2 + 0] = rr[0];
            cms[(h * 7 + c) * 2 + 1] = rr[1];
        }
    }
}

// CLS proj with inlined LSE combine. grid 8 x 256 thr.
__global__ __launch_bounds__(256) void cls_proj_kernel(
    const float* __restrict__ cms, const float* __restrict__ cpv,
    const float* __restrict__ projw, const float* __restrict__ projb,
    float* __restrict__ proj0)
{
    __shared__ float av[512], red[4][64];
    const int b = blockIdx.x, tid = threadIdx.x;
    for (int d = tid; d < 512; d += 256) {
        int h = d >> 6, dd = d & 63;
        float M = -INFINITY;
        #pragma unroll
        for (int c = 0; c < 7; ++c)
            M = fmaxf(M, cms[(h * 7 + c) * 2]);
        float S = 0.f, acc = 0.f;
        #pragma unroll
        for (int c = 0; c < 7; ++c) {
            float e = __expf(cms[(h * 7 + c) * 2] - M);
            S += cms[(h * 7 + c) * 2 + 1] * e;
            acc += cpv[((long)h * 7 + c) * 64 + dd] * e;
        }
        av[d] = acc / S;
    }
    __syncthreads();
    int g = tid >> 6, n = b * 64 + (tid & 63);
    float acc = 0.f;
    for (int k = g * 128; k < g * 128 + 128; ++k)
        acc = fmaf(av[k], projw[(long)k * 512 + n], acc);
    red[g][tid & 63] = acc;
    __syncthreads();
    if (tid < 64)
        proj0[b * 64 + tid] = red[0][tid] + red[1][tid] + red[2][tid]
                              + red[3][tid] + projb[b * 64 + tid];
}

// CLS out: h1[0] + proj0 -> LN -> fc2 -> out[2]. grid 1.
__global__ __launch_bounds__(256) void cls_out_kernel(
    const float* __restrict__ h0, const float* __restrict__ proj0,
    const float* __restrict__ g, const float* __restrict__ b,
    const float* __restrict__ fc2w, const float* __restrict__ fc2b,
    float* __restrict__ out)
{
    const int t = threadIdx.x;
    float v0 = h0[t] + proj0[t];
    float v1 = h0[t + 256] + proj0[t + 256];
    float s = v0 + v1, sq = v0 * v0 + v1 * v1;
    #pragma unroll
    for (int off = 32; off > 0; off >>= 1) {
        s += __shfl_down(s, off);
        sq += __shfl_down(sq, off);
    }
    __shared__ float ps[4], pq[4], pc0[4], pc1[4];
    int w = t >> 6, lane = t & 63;
    if (lane == 0) { ps[w] = s; pq[w] = sq; }
    __syncthreads();
    float Sm = ps[0] + ps[1] + ps[2] + ps[3];
    float Q = pq[0] + pq[1] + pq[2] + pq[3];
    float mean = Sm * (1.f / DIM);
    float var = Q * (1.f / DIM) - mean * mean;
    float inv = rsqrtf(var + LN_EPS);
    float n0 = (v0 - mean) * inv * g[t] + b[t];
    float n1 = (v1 - mean) * inv * g[t + 256] + b[t + 256];
    float c0 = n0 * fc2w[t * 2]     + n1 * fc2w[(t + 256) * 2];
    float c1 = n0 * fc2w[t * 2 + 1] + n1 * fc2w[(t + 256) * 2 + 1];
    #pragma unroll
    for (int off = 32; off > 0; off >>= 1) {
        c0 += __shfl_down(c0, off);
        c1 += __shfl_down(c1, off);
    }
    if (lane == 0) { pc0[w] = c0; pc1[w] = c1; }
    __syncthreads();
    if (t == 0) {
        out[0] = pc0[0] + pc0[1] + pc0[2] + pc0[3] + fc2b[0];
        out[1] = pc1[0] + pc1[1] + pc1[2] + pc1[3] + fc2b[1];
    }
}

// ---------------------------------------------------------------------------
// Mega init: [0,896) fc1 split-K16 -> Pp; [896,1410) CPB angle tables;
// [1410,2039) pair -> (angle idx, frac).
// ---------------------------------------------------------------------------
__global__ __launch_bounds__(256) void mega_kernel(
    const float* __restrict__ hin, const float* __restrict__ fc1_w,
    const float* __restrict__ w1_0, const float* __restrict__ b1_0,
    const float* __restrict__ w2_0, const float* __restrict__ b2_0,
    const float* __restrict__ w1_1, const float* __restrict__ b1_1,
    const float* __restrict__ w2_1, const float* __restrict__ b2_1,
    const float* __restrict__ coords,
    float* __restrict__ Pp, float* __restrict__ T,
    int* __restrict__ pm, float* __restrict__ pf)
{
    __shared__ float smem[2176];
    float (*as)[68] = (float(*)[68])smem;
    float (*bs)[68] = (float(*)[68])(smem + 1088);
    float (*red)[64][8] = (float(*)[64][8])smem;
    const int bid = blockIdx.x, tid = threadIdx.x;

    if (bid < 896) {
        int sk = bid / 56, rem = bid % 56;
        int m0 = (rem % 7) * 64, n0 = (rem / 7) * 64;
        int kBeg = sk * 64, kEnd = kBeg + 64;
        float acc[4][4] = {};
        auto loadA = [&](int k0, float r[4]) {
            r[0]=r[1]=r[2]=r[3]=0.f;
            int gm = m0 + (tid >> 2);
            if (gm >= 400) return;
            int gk = k0 + (tid & 3) * 4;
            float4 v = *(const float4*)(hin + (long)gm * 1024 + gk);
            r[0]=v.x; r[1]=v.y; r[2]=v.z; r[3]=v.w;
        };
        auto loadB = [&](int k0, float r[4]) {
            int gk = k0 + (tid >> 4);
            int gn = n0 + (tid & 15) * 4;
            float4 v = *(const float4*)(fc1_w + (long)gk * 512 + gn);
            r[0]=v.x; r[1]=v.y; r[2]=v.z; r[3]=v.w;
        };
        gemm64<false>(kBeg, kEnd, tid, as, bs, acc, loadA, loadB);
        float* C = Pp + (long)sk * PVS;
        const int tx = tid & 15, ty = tid >> 4;
        #pragma unroll
        for (int r = 0; r < 4; ++r) {
            int m = m0 + ty * 4 + r;
            if (m >= 400) continue;
            *(float4*)&C[(long)m * 512 + n0 + tx * 4] =
                make_float4(acc[r][0], acc[r][1], acc[r][2], acc[r][3]);
        }
    } else if (bid < 1410) {
        int tb = bid - 896;
        int z = tb / 257, ab = tb % 257;
        const float* w1 = z ? w1_1 : w1_0;
        const float* b1 = z ? b1_1 : b1_0;
        const float* w2 = z ? w2_1 : w2_0;
        const float* b2 = z ? b2_1 : b2_0;
        const int lane = tid & 63, wv = tid >> 6;
        float ca = 0.f, sa = 0.f;
        if (ab != 256) {
            float th = fmaf((float)(ab * 64 + lane),
                            (float)(2.0 * M_PI / CPB_M), -(float)M_PI);
            sincosf(th, &sa, &ca);
        } else if (lane == 0) {
            sincosf((float)M_PI, &sa, &ca);  // wrap row; lanes>0 zero-vec
        }
        float a8[8] = {};
        const int kbeg = wv * 128;
        #pragma unroll 4
        for (int k = kbeg; k < kbeg + 128; ++k) {
            float hk = fmaxf(fmaf(ca, w1[k],
                                  fmaf(sa, w1[512 + k], b1[k])), 0.f);
            #pragma unroll
            for (int h2 = 0; h2 < 8; ++h2)
                a8[h2] = fmaf(hk, w2[k * 8 + h2], a8[h2]);
        }
        #pragma unroll
        for (int h2 = 0; h2 < 8; ++h2) red[wv][lane][h2] = a8[h2];
        __syncthreads();
        if (tid < 64) {
            int aidx = ab * 64 + tid;
            #pragma unroll
            for (int h2 = 0; h2 < 8; ++h2)
                T[(long)(z * 8 + h2) * TSTRIDE + aidx] =
                    red[0][tid][h2] + red[1][tid][h2] +
                    red[2][tid][h2] + red[3][tid][h2] + b2[h2];
        }
    } else {
        int p = (bid - 1410) * 256 + tid;
        if (p < NP * NP) {
            int i = p / NP, j = p - i * NP;
            float xi = (i == 0) ? 0.f : coords[(i - 1) * 2];
            float yi = (i == 0) ? 0.f : coords[(i - 1) * 2 + 1];
            float xj = (j == 0) ? 0.f : coords[(j - 1) * 2];
            float yj = (j == 0) ? 0.f : coords[(j - 1) * 2 + 1];
            float rx = xi - xj, ry = yi - yj;
            int mm; float fr;
            if (rx == 0.f && ry == 0.f) {
                mm = CPB_M + 1; fr = 0.f;
            } else {
                float x = (atan2f(ry, rx) + 3.14159265358979f)
                          * (float)(CPB_M / (2.0 * M_PI));
                int mi = (int)x;
                fr = x - (float)mi;
                mm = (mi >= CPB_M) ? mi - CPB_M : mi;
            }
            pm[i * 416 + j] = mm;
            pf[i * 416 + j] = fr;
        }
    }
}

// ---------------------------------------------------------------------------
extern "C" void kernel_launch(void* const* d_in, const int* in_sizes, int n_in,
                              void* d_out, int out_size, void* d_ws, size_t ws_size,
                              hipStream_t stream)
{
    const float* coords = (const float*)d_in[1];
    float* ws = (float*)d_ws;
    float* h0   = ws;                    ws += 401L * 512;
    float* xln  = ws;                    ws += 401L * 512;
    float* S    = ws;                    ws += 8L * PLANE;
    float* T    = ws;                    ws += 16L * TSTRIDE;
    int*   pm   = (int*)ws;              ws += 401L * 416;
    float* pf   = ws;                    ws += 401L * 416;
    float* Pq   = ws;                    ws += 4L * PQS;
    float* qkv  = ws;                    ws += 401L * 1536;
    float* Pv   = ws;                    ws += 4L * PVS;
    float* att  = ws;                    ws += 401L * 512;
    float* Pp   = ws;                    ws += 16L * PVS;
    float* proj0 = ws;                   ws += 512;
    float* cms  = ws;                    ws += 8L * 7 * 2;
    float* cpv  = ws;                    ws += 8L * 7 * 64;

    // phase 0: fc1 (K16) + both CPB angle tables + pair->angle map
    mega_kernel<<<2039, 256, 0, stream>>>(
        (const float*)d_in[0], (const float*)d_in[2],
        (const float*)d_in[7],  (const float*)d_in[8],
        (const float*)d_in[9],  (const float*)d_in[10],
        (const float*)d_in[17], (const float*)d_in[18],
        (const float*)d_in[19], (const float*)d_in[20],
        coords, Pp, T, pm, pf);

    // fc1 reduce + relu + cls + LN(l1) -> h0, xln
    rowfuse_kernel<<<401, 256, 0, stream>>>(
        Pp, PVS, 16, 1, (const float*)d_in[3], 1, nullptr,
        (const float*)d_in[4], h0,
        (const float*)d_in[5], (const float*)d_in[6], xln);

    // -------- layer 1 (full attention) --------
    gemm_split_kernel<<<dim3(7, 24, 4), 256, 0, stream>>>(
        xln, 512, (const float*)d_in[11], 1536, Pq, 1536, PQS,
        401, 1536, 512, 4);
    reduce_kernel<<<602, 256, 0, stream>>>(
        Pq, PQS, 4, (const float*)d_in[12], qkv, 401 * 1536, 1536);
    qk_kernel<<<dim3(7, 7, 8), 256, 0, stream>>>(qkv, pm, pf, T, S);
    softmax_kernel<<<802, 256, 0, stream>>>(S);
    pv_kernel<<<dim3(7, 1, 32), 256, 0, stream>>>(S, qkv, Pv);
    reduce_kernel<<<201, 256, 0, stream>>>(
        Pv, PVS, 4, nullptr, att, 401 * 512, 512);
    proj_kernel<<<dim3(7, 8, 8), 256, 0, stream>>>(
        att, (const float*)d_in[13], Pp);
    rowfuse_kernel<<<401, 256, 0, stream>>>(
        Pp, PVS, 8, 0, (const float*)d_in[14], 0, h0, nullptr, h0,
        (const float*)d_in[15], (const float*)d_in[16], xln);

    // -------- layer 2 (CLS row only, flash-decode on raw partials) --------
    gemm_split_kernel<<<dim3(7, 24, 4), 256, 0, stream>>>(
        xln, 512, (const float*)d_in[21], 1536, Pq, 1536, PQS,
        401, 1536, 512, 4);
    cls_decode_kernel<<<dim3(8, 7), 256, 0, stream>>>(
        Pq, (const float*)d_in[22], pm, pf, T + 8L * TSTRIDE, cms, cpv);
    cls_proj_kernel<<<8, 256, 0, stream>>>(
        cms, cpv, (const float*)d_in[23], (const float*)d_in[24], proj0);
    cls_out_kernel<<<1, 256, 0, stream>>>(
        h0, proj0, (const float*)d_in[25], (const float*)d_in[26],
        (const float*)d_in[27], (const float*)d_in[28], (float*)d_out);
}

// Round 13
// 240.003 us; speedup vs baseline: 2.1422x; 1.0516x over previous
//
#include <hip/hip_runtime.h>
#include <math.h>

#define NP 401            // tokens incl. CLS (400 patches, side=20, add=0)
#define DIM 512
#define LN_EPS 1e-5f
#define ATT_SCALE 0.125f
#define SP 448            // S plane row stride
#define PLANE (NP * SP)
#define CPB_M 4096        // angle-table resolution (interp err ~2e-5 << tol)
#define TSTRIDE (CPB_M + 64)
#define PQS (401L * 1536) // layer-1 qkv partial slice stride
#define PKS (401L * 1024) // layer-2 kv partial slice stride
#define PVS (401L * 512)  // pv / proj partial slice stride

// ---------------------------------------------------------------------------
// 64x64-tile GEMM body: 256 thr, 4x4 micro-tile, K-chunk 16, register
// double-buffered staging via caller-supplied loaders.
// ---------------------------------------------------------------------------
template<bool TB, typename LA, typename LB>
__device__ __forceinline__ void gemm64(
    int kBeg, int kEnd, int tid,
    float (*as)[68], float (*bs)[68], float (&acc)[4][4],
    LA&& loadA, LB&& loadB)
{
    float aR[4], bR[4];
    loadA(kBeg, aR);
    loadB(kBeg, bR);
    for (int k0 = kBeg; k0 < kEnd; k0 += 16) {
        const int arow = tid >> 2, aq = tid & 3;
        as[aq * 4 + 0][arow] = aR[0];
        as[aq * 4 + 1][arow] = aR[1];
        as[aq * 4 + 2][arow] = aR[2];
        as[aq * 4 + 3][arow] = aR[3];
        if (!TB) {
            *(float4*)&bs[tid >> 4][(tid & 15) * 4] =
                make_float4(bR[0], bR[1], bR[2], bR[3]);
        } else {
            bs[aq * 4 + 0][arow] = bR[0];
            bs[aq * 4 + 1][arow] = bR[1];
            bs[aq * 4 + 2][arow] = bR[2];
            bs[aq * 4 + 3][arow] = bR[3];
        }
        __syncthreads();
        float nA[4] = {0.f,0.f,0.f,0.f}, nB[4] = {0.f,0.f,0.f,0.f};
        if (k0 + 16 < kEnd) { loadA(k0 + 16, nA); loadB(k0 + 16, nB); }
        const int tx = tid & 15, ty = tid >> 4;
        #pragma unroll
        for (int kk = 0; kk < 16; ++kk) {
            float4 a4 = *(const float4*)&as[kk][ty * 4];
            float4 b4 = *(const float4*)&bs[kk][tx * 4];
            float av[4] = {a4.x, a4.y, a4.z, a4.w};
            float bv[4] = {b4.x, b4.y, b4.z, b4.w};
            #pragma unroll
            for (int r = 0; r < 4; ++r)
                #pragma unroll
                for (int c = 0; c < 4; ++c)
                    acc[r][c] = fmaf(av[r], bv[c], acc[r][c]);
        }
        __syncthreads();
        #pragma unroll
        for (int j = 0; j < 4; ++j) { aR[j] = nA[j]; bR[j] = nB[j]; }
    }
}

// ---------------------------------------------------------------------------
// Generic split-K GEMM: P[sk] = A[:, slice] @ B[slice, :]  (raw partials)
// ---------------------------------------------------------------------------
__global__ __launch_bounds__(256) void gemm_split_kernel(
    const float* __restrict__ A, int lda,
    const float* __restrict__ B, int ldb,
    float* __restrict__ P, int ldc, long slice,
    int M, int N, int K, int skN)
{
    __shared__ float as[16][68], bs[16][68];
    const int tid = threadIdx.x;
    const int m0 = blockIdx.x * 64, n0 = blockIdx.y * 64;
    const int sk = blockIdx.z;
    const int KS = ((K + skN * 16 - 1) / (skN * 16)) * 16;
    const int kBeg = sk * KS;
    const int kEnd = (kBeg + KS < K) ? kBeg + KS : K;
    float acc[4][4] = {};

    auto loadA = [&](int k0, float r[4]) {
        r[0] = r[1] = r[2] = r[3] = 0.f;
        int gm = m0 + (tid >> 2);
        if (gm >= M) return;
        int gk = k0 + (tid & 3) * 4;
        const float* p = A + (long)gm * lda + gk;
        if (gk + 3 < kEnd) {
            float4 v = *(const float4*)p;
            r[0] = v.x; r[1] = v.y; r[2] = v.z; r[3] = v.w;
        } else {
            #pragma unroll
            for (int j = 0; j < 4; ++j) if (gk + j < kEnd) r[j] = p[j];
        }
    };
    auto loadB = [&](int k0, float r[4]) {
        r[0] = r[1] = r[2] = r[3] = 0.f;
        int gk = k0 + (tid >> 4);
        if (gk >= kEnd) return;
        int gn = n0 + (tid & 15) * 4;
        const float* p = B + (long)gk * ldb + gn;
        float4 v = *(const float4*)p;
        r[0] = v.x; r[1] = v.y; r[2] = v.z; r[3] = v.w;
    };
    if (kBeg < kEnd)
        gemm64<false>(kBeg, kEnd, tid, as, bs, acc, loadA, loadB);

    float* C = P + (long)sk * slice;
    const int tx = tid & 15, ty = tid >> 4;
    #pragma unroll
    for (int r = 0; r < 4; ++r) {
        int m = m0 + ty * 4 + r;
        if (m >= M) continue;
        *(float4*)&C[(long)m * ldc + n0 + tx * 4] =
            make_float4(acc[r][0], acc[r][1], acc[r][2], acc[r][3]);
    }
}

// ---------------------------------------------------------------------------
// Slice reduce: out[i] = sum_sk P[sk][i] (+ bias[i % N]). float4/thread.
// ---------------------------------------------------------------------------
__global__ __launch_bounds__(256) void reduce_kernel(
    const float* __restrict__ P, long slice, int skN,
    const float* __restrict__ bias, float* __restrict__ out,
    int total, int N)
{
    int idx = (blockIdx.x * 256 + threadIdx.x) * 4;
    if (idx >= total) return;
    float4 s = *(const float4*)(P + idx);
    for (int k = 1; k < skN; ++k) {
        float4 p = *(const float4*)(P + (long)k * slice + idx);
        s.x += p.x; s.y += p.y; s.z += p.z; s.w += p.w;
    }
    if (bias) {
        const float4 b = *(const float4*)(bias + (idx % N));
        s.x += b.x; s.y += b.y; s.z += b.z; s.w += b.w;
    }
    *(float4*)(out + idx) = s;
}

// ---------------------------------------------------------------------------
// QK^T (layer 1): dense qkv staging; CPB bias interp epilogue. grid (7,7,8).
// ---------------------------------------------------------------------------
__global__ __launch_bounds__(256) void qk_kernel(
    const float* __restrict__ qkv,
    const int* __restrict__ pm, const float* __restrict__ pf,
    const float* __restrict__ T, float* __restrict__ S)
{
    __shared__ float as[16][68], bs[16][68];
    const int tid = threadIdx.x;
    const int m0 = blockIdx.x * 64, n0 = blockIdx.y * 64, h = blockIdx.z;
    float acc[4][4] = {};

    auto loadQ = [&](int k0, float r[4]) {
        int gm = m0 + (tid >> 2);
        if (gm > 400) { r[0]=r[1]=r[2]=r[3]=0.f; return; }
        int gk = k0 + (tid & 3) * 4;
        float4 v = *(const float4*)(qkv + (long)gm * 1536 + h * 64 + gk);
        r[0]=v.x; r[1]=v.y; r[2]=v.z; r[3]=v.w;
    };
    auto loadK = [&](int k0, float r[4]) {
        int gn = n0 + (tid >> 2);
        if (gn > 400) { r[0]=r[1]=r[2]=r[3]=0.f; return; }
        int gk = k0 + (tid & 3) * 4;
        float4 v = *(const float4*)(qkv + (long)gn * 1536 + 512 + h * 64 + gk);
        r[0]=v.x; r[1]=v.y; r[2]=v.z; r[3]=v.w;
    };
    gemm64<true>(0, 64, tid, as, bs, acc, loadQ, loadK);

    const int tx = tid & 15, ty = tid >> 4;
    const float* Tt = T + (long)h * TSTRIDE;
    float* Sp = S + (long)h * PLANE;
    #pragma unroll
    for (int r = 0; r < 4; ++r) {
        int i = m0 + ty * 4 + r;
        if (i > 400) continue;
        #pragma unroll
        for (int c = 0; c < 4; ++c) {
            int j = n0 + tx * 4 + c;
            if (j > 400) continue;
            int id = i * 416 + j;
            int mm = pm[id];
            float fr = pf[id];
            float t0 = Tt[mm], t1 = Tt[mm + 1];
            Sp[(long)i * SP + j] =
                fmaf(acc[r][c], ATT_SCALE, fmaf(fr, t1 - t0, t0));
        }
    }
}

// ---------------------------------------------------------------------------
// Softmax, wave-per-row. grid 802 x 256 thr (4 rows/block).
// ---------------------------------------------------------------------------
__global__ __launch_bounds__(256) void softmax_kernel(float* __restrict__ S)
{
    int r = blockIdx.x * 4 + (threadIdx.x >> 6);
    if (r >= 3208) return;
    int hh = r / 401, i = r - hh * 401;
    float* row = S + (long)hh * PLANE + (long)i * SP;
    int lane = threadIdx.x & 63;
    float v[7], mx = -INFINITY;
    #pragma unroll
    for (int j = 0; j < 7; ++j) {
        int c = lane + j * 64;
        v[j] = (c < NP) ? row[c] : -INFINITY;
        mx = fmaxf(mx, v[j]);
    }
    #pragma unroll
    for (int off = 32; off > 0; off >>= 1)
        mx = fmaxf(mx, __shfl_xor(mx, off));
    float s = 0.f;
    #pragma unroll
    for (int j = 0; j < 7; ++j) {
        v[j] = (lane + j * 64 < NP) ? __expf(v[j] - mx) : 0.f;
        s += v[j];
    }
    #pragma unroll
    for (int off = 32; off > 0; off >>= 1)
        s += __shfl_xor(s, off);
    float inv = 1.f / s;
    #pragma unroll
    for (int j = 0; j < 7; ++j) {
        int c = lane + j * 64;
        if (c < NP) row[c] = v[j] * inv;
    }
}

// ---------------------------------------------------------------------------
// PV (layer 1), split-K4 over keys, dense V. grid (7,1,32): z = h*4 + sk.
// ---------------------------------------------------------------------------
__global__ __launch_bounds__(256) void pv_kernel(
    const float* __restrict__ S, const float* __restrict__ qkv,
    float* __restrict__ Pv)
{
    __shared__ float as[16][68], bs[16][68];
    const int tid = threadIdx.x;
    const int m0 = blockIdx.x * 64;
    const int h = blockIdx.z >> 2, sk = blockIdx.z & 3;
    const int kBeg = sk * 112;
    const int kEnd = (kBeg + 112 < NP) ? kBeg + 112 : NP;
    float acc[4][4] = {};

    auto loadA = [&](int k0, float r[4]) {
        r[0] = r[1] = r[2] = r[3] = 0.f;
        int gm = m0 + (tid >> 2);
        if (gm > 400) return;
        int gk = k0 + (tid & 3) * 4;
        const float* p = S + (long)h * PLANE + (long)gm * SP + gk;
        if (gk + 3 < kEnd) {
            float4 v = *(const float4*)p;
            r[0]=v.x; r[1]=v.y; r[2]=v.z; r[3]=v.w;
        } else {
            #pragma unroll
            for (int j = 0; j < 4; ++j) if (gk + j < kEnd) r[j] = p[j];
        }
    };
    auto loadB = [&](int k0, float r[4]) {
        r[0] = r[1] = r[2] = r[3] = 0.f;
        int key = k0 + (tid >> 4);
        if (key >= kEnd) return;
        int d = (tid & 15) * 4;
        float4 v = *(const float4*)(qkv + (long)key * 1536 + 1024 + h * 64 + d);
        r[0]=v.x; r[1]=v.y; r[2]=v.z; r[3]=v.w;
    };
    gemm64<false>(kBeg, kEnd, tid, as, bs, acc, loadA, loadB);

    float* C = Pv + (long)sk * PVS;
    const int tx = tid & 15, ty = tid >> 4;
    #pragma unroll
    for (int r = 0; r < 4; ++r) {
        int m = m0 + ty * 4 + r;
        if (m > 400) continue;
        *(float4*)&C[(long)m * 512 + h * 64 + tx * 4] =
            make_float4(acc[r][0], acc[r][1], acc[r][2], acc[r][3]);
    }
}

// ---------------------------------------------------------------------------
// proj (layer 1), split-K8, dense att. grid (7,8,8).
// ---------------------------------------------------------------------------
__global__ __launch_bounds__(256) void proj_kernel(
    const float* __restrict__ att, const float* __restrict__ projw,
    float* __restrict__ Pp)
{
    __shared__ float as[16][68], bs[16][68];
    const int tid = threadIdx.x;
    const int m0 = blockIdx.x * 64, n0 = blockIdx.y * 64, sk = blockIdx.z;
    const int kBeg = sk * 64, kEnd = kBeg + 64;
    float acc[4][4] = {};

    auto loadA = [&](int k0, float r[4]) {
        r[0] = r[1] = r[2] = r[3] = 0.f;
        int gm = m0 + (tid >> 2);
        if (gm > 400) return;
        int gk = k0 + (tid & 3) * 4;
        float4 v = *(const float4*)(att + (long)gm * 512 + gk);
        r[0]=v.x; r[1]=v.y; r[2]=v.z; r[3]=v.w;
    };
    auto loadB = [&](int k0, float r[4]) {
        int gk = k0 + (tid >> 4);
        int gn = n0 + (tid & 15) * 4;
        float4 v = *(const float4*)(projw + (long)gk * 512 + gn);
        r[0]=v.x; r[1]=v.y; r[2]=v.z; r[3]=v.w;
    };
    gemm64<false>(kBeg, kEnd, tid, as, bs, acc, loadA, loadB);

    float* C = Pp + (long)sk * PVS;
    const int tx = tid & 15, ty = tid >> 4;
    #pragma unroll
    for (int r = 0; r < 4; ++r) {
        int m = m0 + ty * 4 + r;
        if (m > 400) continue;
        *(float4*)&C[(long)m * 512 + n0 + tx * 4] =
            make_float4(acc[r][0], acc[r][1], acc[r][2], acc[r][3]);
    }
}

// ---------------------------------------------------------------------------
// Per-row split-K reduce + epilogue + LayerNorm. grid 401.
// ---------------------------------------------------------------------------
__global__ __launch_bounds__(256) void rowfuse_kernel(
    const float* __restrict__ P, long slice, int skN, int rowOff,
    const float* __restrict__ bias, int doRelu,
    const float* __restrict__ resid, const float* __restrict__ cls,
    float* __restrict__ h0,
    const float* __restrict__ g, const float* __restrict__ b,
    float* __restrict__ xln)
{
    const int r = blockIdx.x, t = threadIdx.x;
    float v0, v1;
    if (cls && r == 0) {
        v0 = cls[t]; v1 = cls[t + 256];
    } else {
        const float* p = P + (long)(r - rowOff) * DIM;
        v0 = bias[t]; v1 = bias[t + 256];
        for (int k = 0; k < skN; ++k) {
            v0 += p[(long)k * slice + t];
            v1 += p[(long)k * slice + t + 256];
        }
        if (resid) {
            v0 += resid[(long)r * DIM + t];
            v1 += resid[(long)r * DIM + t + 256];
        }
        if (doRelu) { v0 = fmaxf(v0, 0.f); v1 = fmaxf(v1, 0.f); }
    }
    h0[(long)r * DIM + t] = v0;
    h0[(long)r * DIM + t + 256] = v1;

    float s = v0 + v1, sq = v0 * v0 + v1 * v1;
    #pragma unroll
    for (int off = 32; off > 0; off >>= 1) {
        s += __shfl_down(s, off);
        sq += __shfl_down(sq, off);
    }
    __shared__ float ps[4], pq[4];
    int w = t >> 6, lane = t & 63;
    if (lane == 0) { ps[w] = s; pq[w] = sq; }
    __syncthreads();
    float Sm = ps[0] + ps[1] + ps[2] + ps[3];
    float Q = pq[0] + pq[1] + pq[2] + pq[3];
    float mean = Sm * (1.f / DIM);
    float var = Q * (1.f / DIM) - mean * mean;
    float inv = rsqrtf(var + LN_EPS);
    xln[(long)r * DIM + t]       = (v0 - mean) * inv * g[t] + b[t];
    xln[(long)r * DIM + t + 256] = (v1 - mean) * inv * g[t + 256] + b[t + 256];
}

// ---------------------------------------------------------------------------
// CLS flash-decode (layer 2): grid (8 heads, 7 key-chunks of 64).
// q0 computed inline from xln row 0 (weights L2-hot); K/V read from the
// 4 kv split-K partial slices + bias inline (consumed exactly once).
// ---------------------------------------------------------------------------
__global__ __launch_bounds__(256) void cls_decode_kernel(
    const float* __restrict__ xln, const float* __restrict__ qkvw,
    const float* __restrict__ Pkv, const float* __restrict__ qkvb,
    const int* __restrict__ pm, const float* __restrict__ pf,
    const float* __restrict__ T,
    float* __restrict__ cms, float* __restrict__ cpv)
{
    const int h = blockIdx.x, c = blockIdx.y, tid = threadIdx.x;
    const int kBeg = c * 64;
    __shared__ float q0[64], scraw[64], p[64], red[4][64], rr[2];

    // q0[d] = sum_k xln[0][k] * Wq[k][h*64+d] + bq[h*64+d]; 4-wave k-split
    {
        int d = tid & 63, w4 = tid >> 6;
        const float* col = qkvw + h * 64 + d;
        float acc = 0.f;
        for (int k = w4 * 128; k < w4 * 128 + 128; ++k)
            acc = fmaf(xln[k], col[(long)k * 1536], acc);
        red[w4][d] = acc;
    }
    __syncthreads();
    if (tid < 64)
        q0[tid] = red[0][tid] + red[1][tid] + red[2][tid] + red[3][tid]
                  + qkvb[h * 64 + tid];
    __syncthreads();

    // scores: key k = tid>>2 (4 lanes/key, 16 dims each), shuffle-reduce
    {
        int k = tid >> 2, q = tid & 3;
        int j = kBeg + k;
        float dot = 0.f;
        if (j < NP) {
            long base = (long)j * 1024 + h * 64 + q * 16;   // K cols 0..512
            #pragma unroll
            for (int d = 0; d < 16; d += 4) {
                float4 x0 = *(const float4*)(Pkv + base + d);
                float4 x1 = *(const float4*)(Pkv + PKS + base + d);
                float4 x2 = *(const float4*)(Pkv + 2 * PKS + base + d);
                float4 x3 = *(const float4*)(Pkv + 3 * PKS + base + d);
                float4 bb = *(const float4*)(qkvb + 512 + h * 64 + q * 16 + d);
                float4 qq = *(const float4*)(q0 + q * 16 + d);
                dot = fmaf(qq.x, x0.x + x1.x + x2.x + x3.x + bb.x, dot);
                dot = fmaf(qq.y, x0.y + x1.y + x2.y + x3.y + bb.y, dot);
                dot = fmaf(qq.z, x0.z + x1.z + x2.z + x3.z + bb.z, dot);
                dot = fmaf(qq.w, x0.w + x1.w + x2.w + x3.w + bb.w, dot);
            }
        }
        dot += __shfl_down(dot, 2);
        dot += __shfl_down(dot, 1);
        if (q == 0) scraw[k] = dot;
    }
    __syncthreads();

    // bias + local softmax on wave 0
    if (tid < 64) {
        int j = kBeg + tid;
        float s;
        if (j < NP) {
            int mm = pm[j];                   // row 0 of pair map
            float fr = pf[j];
            const float* Tt = T + (long)h * TSTRIDE;
            float t0 = Tt[mm], t1 = Tt[mm + 1];
            s = fmaf(scraw[tid], ATT_SCALE, fmaf(fr, t1 - t0, t0));
        } else {
            s = -INFINITY;
        }
        float m = s;
        #pragma unroll
        for (int off = 32; off > 0; off >>= 1)
            m = fmaxf(m, __shfl_xor(m, off));
        float e = (j < NP) ? __expf(s - m) : 0.f;
        float sum = e;
        #pragma unroll
        for (int off = 32; off > 0; off >>= 1)
            sum += __shfl_xor(sum, off);
        p[tid] = e;
        if (tid == 0) { rr[0] = m; rr[1] = sum; }
    }
    __syncthreads();

    // partial PV: d = lane, wave w handles keys k ≡ w (mod 4)
    {
        int w = tid >> 6, d = tid & 63;
        float vb = qkvb[1024 + h * 64 + d];
        float acc = 0.f;
        for (int k = w; k < 64; k += 4) {
            int j = kBeg + k;
            if (j >= NP) break;
            long o = (long)j * 1024 + 512 + h * 64 + d;     // V cols 512..1024
            float v = Pkv[o] + Pkv[PKS + o] + Pkv[2 * PKS + o]
                      + Pkv[3 * PKS + o] + vb;
            acc = fmaf(p[k], v, acc);
        }
        red[w][d] = acc;
    }
    __syncthreads();
    if (tid < 64) {
        cpv[((long)h * 7 + c) * 64 + tid] =
            red[0][tid] + red[1][tid] + red[2][tid] + red[3][tid];
        if (tid == 0) {
            cms[(h * 7 + c) * 2 + 0] = rr[0];
            cms[(h * 7 + c) * 2 + 1] = rr[1];
        }
    }
}

// CLS proj with inlined LSE combine. grid 8 x 256 thr.
__global__ __launch_bounds__(256) void cls_proj_kernel(
    const float* __restrict__ cms, const float* __restrict__ cpv,
    const float* __restrict__ projw, const float* __restrict__ projb,
    float* __restrict__ proj0)
{
    __shared__ float av[512], red[4][64];
    const int b = blockIdx.x, tid = threadIdx.x;
    for (int d = tid; d < 512; d += 256) {
        int h = d >> 6, dd = d & 63;
        float M = -INFINITY;
        #pragma unroll
        for (int c = 0; c < 7; ++c)
            M = fmaxf(M, cms[(h * 7 + c) * 2]);
        float S = 0.f, acc = 0.f;
        #pragma unroll
        for (int c = 0; c < 7; ++c) {
            float e = __expf(cms[(h * 7 + c) * 2] - M);
            S += cms[(h * 7 + c) * 2 + 1] * e;
            acc += cpv[((long)h * 7 + c) * 64 + dd] * e;
        }
        av[d] = acc / S;
    }
    __syncthreads();
    int g = tid >> 6, n = b * 64 + (tid & 63);
    float acc = 0.f;
    for (int k = g * 128; k < g * 128 + 128; ++k)
        acc = fmaf(av[k], projw[(long)k * 512 + n], acc);
    red[g][tid & 63] = acc;
    __syncthreads();
    if (tid < 64)
        proj0[b * 64 + tid] = red[0][tid] + red[1][tid] + red[2][tid]
                              + red[3][tid] + projb[b * 64 + tid];
}

// CLS out: h1[0] + proj0 -> LN -> fc2 -> out[2]. grid 1.
__global__ __launch_bounds__(256) void cls_out_kernel(
    const float* __restrict__ h0, const float* __restrict__ proj0,
    const float* __restrict__ g, const float* __restrict__ b,
    const float* __restrict__ fc2w, const float* __restrict__ fc2b,
    float* __restrict__ out)
{
    const int t = threadIdx.x;
    float v0 = h0[t] + proj0[t];
    float v1 = h0[t + 256] + proj0[t + 256];
    float s = v0 + v1, sq = v0 * v0 + v1 * v1;
    #pragma unroll
    for (int off = 32; off > 0; off >>= 1) {
        s += __shfl_down(s, off);
        sq += __shfl_down(sq, off);
    }
    __shared__ float ps[4], pq[4], pc0[4], pc1[4];
    int w = t >> 6, lane = t & 63;
    if (lane == 0) { ps[w] = s; pq[w] = sq; }
    __syncthreads();
    float Sm = ps[0] + ps[1] + ps[2] + ps[3];
    float Q = pq[0] + pq[1] + pq[2] + pq[3];
    float mean = Sm * (1.f / DIM);
    float var = Q * (1.f / DIM) - mean * mean;
    float inv = rsqrtf(var + LN_EPS);
    float n0 = (v0 - mean) * inv * g[t] + b[t];
    float n1 = (v1 - mean) * inv * g[t + 256] + b[t + 256];
    float c0 = n0 * fc2w[t * 2]     + n1 * fc2w[(t + 256) * 2];
    float c1 = n0 * fc2w[t * 2 + 1] + n1 * fc2w[(t + 256) * 2 + 1];
    #pragma unroll
    for (int off = 32; off > 0; off >>= 1) {
        c0 += __shfl_down(c0, off);
        c1 += __shfl_down(c1, off);
    }
    if (lane == 0) { pc0[w] = c0; pc1[w] = c1; }
    __syncthreads();
    if (t == 0) {
        out[0] = pc0[0] + pc0[1] + pc0[2] + pc0[3] + fc2b[0];
        out[1] = pc1[0] + pc1[1] + pc1[2] + pc1[3] + fc2b[1];
    }
}

// ---------------------------------------------------------------------------
// Mega init: [0,896) fc1 split-K16 -> Pp; [896,1026) CPB angle tables
// (65 blocks/layer at CPB_M=4096); [1026,1655) pair -> (angle idx, frac).
// ---------------------------------------------------------------------------
__global__ __launch_bounds__(256) void mega_kernel(
    const float* __restrict__ hin, const float* __restrict__ fc1_w,
    const float* __restrict__ w1_0, const float* __restrict__ b1_0,
    const float* __restrict__ w2_0, const float* __restrict__ b2_0,
    const float* __restrict__ w1_1, const float* __restrict__ b1_1,
    const float* __restrict__ w2_1, const float* __restrict__ b2_1,
    const float* __restrict__ coords,
    float* __restrict__ Pp, float* __restrict__ T,
    int* __restrict__ pm, float* __restrict__ pf)
{
    __shared__ float smem[2176];
    float (*as)[68] = (float(*)[68])smem;
    float (*bs)[68] = (float(*)[68])(smem + 1088);
    float (*red)[64][8] = (float(*)[64][8])smem;
    const int bid = blockIdx.x, tid = threadIdx.x;

    if (bid < 896) {
        int sk = bid / 56, rem = bid % 56;
        int m0 = (rem % 7) * 64, n0 = (rem / 7) * 64;
        int kBeg = sk * 64, kEnd = kBeg + 64;
        float acc[4][4] = {};
        auto loadA = [&](int k0, float r[4]) {
            r[0]=r[1]=r[2]=r[3]=0.f;
            int gm = m0 + (tid >> 2);
            if (gm >= 400) return;
            int gk = k0 + (tid & 3) * 4;
            float4 v = *(const float4*)(hin + (long)gm * 1024 + gk);
            r[0]=v.x; r[1]=v.y; r[2]=v.z; r[3]=v.w;
        };
        auto loadB = [&](int k0, float r[4]) {
            int gk = k0 + (tid >> 4);
            int gn = n0 + (tid & 15) * 4;
            float4 v = *(const float4*)(fc1_w + (long)gk * 512 + gn);
            r[0]=v.x; r[1]=v.y; r[2]=v.z; r[3]=v.w;
        };
        gemm64<false>(kBeg, kEnd, tid, as, bs, acc, loadA, loadB);
        float* C = Pp + (long)sk * PVS;
        const int tx = tid & 15, ty = tid >> 4;
        #pragma unroll
        for (int r = 0; r < 4; ++r) {
            int m = m0 + ty * 4 + r;
            if (m >= 400) continue;
            *(float4*)&C[(long)m * 512 + n0 + tx * 4] =
                make_float4(acc[r][0], acc[r][1], acc[r][2], acc[r][3]);
        }
    } else if (bid < 1026) {
        int tb = bid - 896;
        int z = tb / 65, ab = tb % 65;
        const float* w1 = z ? w1_1 : w1_0;
        const float* b1 = z ? b1_1 : b1_0;
        const float* w2 = z ? w2_1 : w2_0;
        const float* b2 = z ? b2_1 : b2_0;
        const int lane = tid & 63, wv = tid >> 6;
        float ca = 0.f, sa = 0.f;
        if (ab != 64) {
            float th = fmaf((float)(ab * 64 + lane),
                            (float)(2.0 * M_PI / CPB_M), -(float)M_PI);
            sincosf(th, &sa, &ca);
        } else if (lane == 0) {
            sincosf((float)M_PI, &sa, &ca);  // wrap row; lanes>0 zero-vec
        }
        float a8[8] = {};
        const int kbeg = wv * 128;
        #pragma unroll 4
        for (int k = kbeg; k < kbeg + 128; ++k) {
            float hk = fmaxf(fmaf(ca, w1[k],
                                  fmaf(sa, w1[512 + k], b1[k])), 0.f);
            #pragma unroll
            for (int h2 = 0; h2 < 8; ++h2)
                a8[h2] = fmaf(hk, w2[k * 8 + h2], a8[h2]);
        }
        #pragma unroll
        for (int h2 = 0; h2 < 8; ++h2) red[wv][lane][h2] = a8[h2];
        __syncthreads();
        if (tid < 64) {
            int aidx = ab * 64 + tid;
            if (aidx <= CPB_M + 1) {
                #pragma unroll
                for (int h2 = 0; h2 < 8; ++h2)
                    T[(long)(z * 8 + h2) * TSTRIDE + aidx] =
                        red[0][tid][h2] + red[1][tid][h2] +
                        red[2][tid][h2] + red[3][tid][h2] + b2[h2];
            }
        }
    } else {
        int p = (bid - 1026) * 256 + tid;
        if (p < NP * NP) {
            int i = p / NP, j = p - i * NP;
            float xi = (i == 0) ? 0.f : coords[(i - 1) * 2];
            float yi = (i == 0) ? 0.f : coords[(i - 1) * 2 + 1];
            float xj = (j == 0) ? 0.f : coords[(j - 1) * 2];
            float yj = (j == 0) ? 0.f : coords[(j - 1) * 2 + 1];
            float rx = xi - xj, ry = yi - yj;
            int mm; float fr;
            if (rx == 0.f && ry == 0.f) {
                mm = CPB_M + 1; fr = 0.f;
            } else {
                float x = (atan2f(ry, rx) + 3.14159265358979f)
                          * (float)(CPB_M / (2.0 * M_PI));
                int mi = (int)x;
                fr = x - (float)mi;
                mm = (mi >= CPB_M) ? mi - CPB_M : mi;
            }
            pm[i * 416 + j] = mm;
            pf[i * 416 + j] = fr;
        }
    }
}

// ---------------------------------------------------------------------------
extern "C" void kernel_launch(void* const* d_in, const int* in_sizes, int n_in,
                              void* d_out, int out_size, void* d_ws, size_t ws_size,
                              hipStream_t stream)
{
    const float* coords = (const float*)d_in[1];
    float* ws = (float*)d_ws;
    float* h0   = ws;                    ws += 401L * 512;
    float* xln  = ws;                    ws += 401L * 512;
    float* S    = ws;                    ws += 8L * PLANE;
    float* T    = ws;                    ws += 16L * TSTRIDE;
    int*   pm   = (int*)ws;              ws += 401L * 416;
    float* pf   = ws;                    ws += 401L * 416;
    float* Pq   = ws;                    ws += 4L * PQS;   // also layer-2 kv
    float* qkv  = ws;                    ws += 401L * 1536;
    float* Pv   = ws;                    ws += 4L * PVS;
    float* att  = ws;                    ws += 401L * 512;
    float* Pp   = ws;                    ws += 16L * PVS;
    float* proj0 = ws;                   ws += 512;
    float* cms  = ws;                    ws += 8L * 7 * 2;
    float* cpv  = ws;                    ws += 8L * 7 * 64;

    // phase 0: fc1 (K16) + both CPB angle tables + pair->angle map
    mega_kernel<<<1655, 256, 0, stream>>>(
        (const float*)d_in[0], (const float*)d_in[2],
        (const float*)d_in[7],  (const float*)d_in[8],
        (const float*)d_in[9],  (const float*)d_in[10],
        (const float*)d_in[17], (const float*)d_in[18],
        (const float*)d_in[19], (const float*)d_in[20],
        coords, Pp, T, pm, pf);

    // fc1 reduce + relu + cls + LN(l1) -> h0, xln
    rowfuse_kernel<<<401, 256, 0, stream>>>(
        Pp, PVS, 16, 1, (const float*)d_in[3], 1, nullptr,
        (const float*)d_in[4], h0,
        (const float*)d_in[5], (const float*)d_in[6], xln);

    // -------- layer 1 (full attention) --------
    gemm_split_kernel<<<dim3(7, 24, 4), 256, 0, stream>>>(
        xln, 512, (const float*)d_in[11], 1536, Pq, 1536, PQS,
        401, 1536, 512, 4);
    reduce_kernel<<<602, 256, 0, stream>>>(
        Pq, PQS, 4, (const float*)d_in[12], qkv, 401 * 1536, 1536);
    qk_kernel<<<dim3(7, 7, 8), 256, 0, stream>>>(qkv, pm, pf, T, S);
    softmax_kernel<<<802, 256, 0, stream>>>(S);
    pv_kernel<<<dim3(7, 1, 32), 256, 0, stream>>>(S, qkv, Pv);
    reduce_kernel<<<201, 256, 0, stream>>>(
        Pv, PVS, 4, nullptr, att, 401 * 512, 512);
    proj_kernel<<<dim3(7, 8, 8), 256, 0, stream>>>(
        att, (const float*)d_in[13], Pp);
    rowfuse_kernel<<<401, 256, 0, stream>>>(
        Pp, PVS, 8, 0, (const float*)d_in[14], 0, h0, nullptr, h0,
        (const float*)d_in[15], (const float*)d_in[16], xln);

    // -------- layer 2: K,V only GEMM (cols 512..1536), CLS flash-decode ----
    gemm_split_kernel<<<dim3(7, 16, 4), 256, 0, stream>>>(
        xln, 512, (const float*)d_in[21] + 512, 1536, Pq, 1024, PKS,
        401, 1024, 512, 4);
    cls_decode_kernel<<<dim3(8, 7), 256, 0, stream>>>(
        xln, (const float*)d_in[21], Pq, (const float*)d_in[22],
        pm, pf, T + 8L * TSTRIDE, cms, cpv);
    cls_proj_kernel<<<8, 256, 0, stream>>>(
        cms, cpv, (const float*)d_in[23], (const float*)d_in[24], proj0);
    cls_out_kernel<<<1, 256, 0, stream>>>(
        h0, proj0, (const float*)d_in[25], (const float*)d_in[26],
        (const float*)d_in[27], (const float*)d_in[28], (float*)d_out);
}

// Round 14
// 237.411 us; speedup vs baseline: 2.1656x; 1.0109x over previous
//
#include <hip/hip_runtime.h>
#include <math.h>

#define NP 401            // tokens incl. CLS (400 patches, side=20, add=0)
#define DIM 512
#define LN_EPS 1e-5f
#define ATT_SCALE 0.125f
#define SP 448            // S plane row stride
#define PLANE (NP * SP)
#define CPB_M 4096        // angle-table resolution (interp err ~2e-5 << tol)
#define TSTRIDE (CPB_M + 64)
#define PQS (401L * 1536) // layer-1 qkv partial slice stride
#define PKS (401L * 1024) // layer-2 kv partial slice stride
#define PVS (401L * 512)  // pv / proj partial slice stride

// ---------------------------------------------------------------------------
// 64x64-tile GEMM body: 256 thr, 4x4 micro-tile, K-chunk 16, register
// double-buffered staging via caller-supplied loaders.
// ---------------------------------------------------------------------------
template<bool TB, typename LA, typename LB>
__device__ __forceinline__ void gemm64(
    int kBeg, int kEnd, int tid,
    float (*as)[68], float (*bs)[68], float (&acc)[4][4],
    LA&& loadA, LB&& loadB)
{
    float aR[4], bR[4];
    loadA(kBeg, aR);
    loadB(kBeg, bR);
    for (int k0 = kBeg; k0 < kEnd; k0 += 16) {
        const int arow = tid >> 2, aq = tid & 3;
        as[aq * 4 + 0][arow] = aR[0];
        as[aq * 4 + 1][arow] = aR[1];
        as[aq * 4 + 2][arow] = aR[2];
        as[aq * 4 + 3][arow] = aR[3];
        if (!TB) {
            *(float4*)&bs[tid >> 4][(tid & 15) * 4] =
                make_float4(bR[0], bR[1], bR[2], bR[3]);
        } else {
            bs[aq * 4 + 0][arow] = bR[0];
            bs[aq * 4 + 1][arow] = bR[1];
            bs[aq * 4 + 2][arow] = bR[2];
            bs[aq * 4 + 3][arow] = bR[3];
        }
        __syncthreads();
        float nA[4] = {0.f,0.f,0.f,0.f}, nB[4] = {0.f,0.f,0.f,0.f};
        if (k0 + 16 < kEnd) { loadA(k0 + 16, nA); loadB(k0 + 16, nB); }
        const int tx = tid & 15, ty = tid >> 4;
        #pragma unroll
        for (int kk = 0; kk < 16; ++kk) {
            float4 a4 = *(const float4*)&as[kk][ty * 4];
            float4 b4 = *(const float4*)&bs[kk][tx * 4];
            float av[4] = {a4.x, a4.y, a4.z, a4.w};
            float bv[4] = {b4.x, b4.y, b4.z, b4.w};
            #pragma unroll
            for (int r = 0; r < 4; ++r)
                #pragma unroll
                for (int c = 0; c < 4; ++c)
                    acc[r][c] = fmaf(av[r], bv[c], acc[r][c]);
        }
        __syncthreads();
        #pragma unroll
        for (int j = 0; j < 4; ++j) { aR[j] = nA[j]; bR[j] = nB[j]; }
    }
}

// ---------------------------------------------------------------------------
// Generic split-K GEMM: P[sk] = A[:, slice] @ B[slice, :]  (raw partials)
// ---------------------------------------------------------------------------
__global__ __launch_bounds__(256) void gemm_split_kernel(
    const float* __restrict__ A, int lda,
    const float* __restrict__ B, int ldb,
    float* __restrict__ P, int ldc, long slice,
    int M, int N, int K, int skN)
{
    __shared__ float as[16][68], bs[16][68];
    const int tid = threadIdx.x;
    const int m0 = blockIdx.x * 64, n0 = blockIdx.y * 64;
    const int sk = blockIdx.z;
    const int KS = ((K + skN * 16 - 1) / (skN * 16)) * 16;
    const int kBeg = sk * KS;
    const int kEnd = (kBeg + KS < K) ? kBeg + KS : K;
    float acc[4][4] = {};

    auto loadA = [&](int k0, float r[4]) {
        r[0] = r[1] = r[2] = r[3] = 0.f;
        int gm = m0 + (tid >> 2);
        if (gm >= M) return;
        int gk = k0 + (tid & 3) * 4;
        const float* p = A + (long)gm * lda + gk;
        if (gk + 3 < kEnd) {
            float4 v = *(const float4*)p;
            r[0] = v.x; r[1] = v.y; r[2] = v.z; r[3] = v.w;
        } else {
            #pragma unroll
            for (int j = 0; j < 4; ++j) if (gk + j < kEnd) r[j] = p[j];
        }
    };
    auto loadB = [&](int k0, float r[4]) {
        r[0] = r[1] = r[2] = r[3] = 0.f;
        int gk = k0 + (tid >> 4);
        if (gk >= kEnd) return;
        int gn = n0 + (tid & 15) * 4;
        const float* p = B + (long)gk * ldb + gn;
        float4 v = *(const float4*)p;
        r[0] = v.x; r[1] = v.y; r[2] = v.z; r[3] = v.w;
    };
    if (kBeg < kEnd)
        gemm64<false>(kBeg, kEnd, tid, as, bs, acc, loadA, loadB);

    float* C = P + (long)sk * slice;
    const int tx = tid & 15, ty = tid >> 4;
    #pragma unroll
    for (int r = 0; r < 4; ++r) {
        int m = m0 + ty * 4 + r;
        if (m >= M) continue;
        *(float4*)&C[(long)m * ldc + n0 + tx * 4] =
            make_float4(acc[r][0], acc[r][1], acc[r][2], acc[r][3]);
    }
}

// ---------------------------------------------------------------------------
// Slice reduce: out[i] = sum_sk P[sk][i] (+ bias[i % N]). float4/thread.
// ---------------------------------------------------------------------------
__global__ __launch_bounds__(256) void reduce_kernel(
    const float* __restrict__ P, long slice, int skN,
    const float* __restrict__ bias, float* __restrict__ out,
    int total, int N)
{
    int idx = (blockIdx.x * 256 + threadIdx.x) * 4;
    if (idx >= total) return;
    float4 s = *(const float4*)(P + idx);
    for (int k = 1; k < skN; ++k) {
        float4 p = *(const float4*)(P + (long)k * slice + idx);
        s.x += p.x; s.y += p.y; s.z += p.z; s.w += p.w;
    }
    if (bias) {
        const float4 b = *(const float4*)(bias + (idx % N));
        s.x += b.x; s.y += b.y; s.z += b.z; s.w += b.w;
    }
    *(float4*)(out + idx) = s;
}

// ---------------------------------------------------------------------------
// QK^T (layer 1): dense qkv staging; CPB bias interp epilogue; writes RAW
// biased scores to S, plus per-(row, n-block) LSE partials (m, sum) to Sml.
// grid (7,7,8).
// ---------------------------------------------------------------------------
__global__ __launch_bounds__(256) void qk_kernel(
    const float* __restrict__ qkv,
    const int* __restrict__ pm, const float* __restrict__ pf,
    const float* __restrict__ T, float* __restrict__ S,
    float* __restrict__ Sml)            // (8,401,7,2)
{
    __shared__ float as[16][68], bs[16][68];
    const int tid = threadIdx.x;
    const int m0 = blockIdx.x * 64, n0 = blockIdx.y * 64, h = blockIdx.z;
    const int nb = blockIdx.y;
    float acc[4][4] = {};

    auto loadQ = [&](int k0, float r[4]) {
        int gm = m0 + (tid >> 2);
        if (gm > 400) { r[0]=r[1]=r[2]=r[3]=0.f; return; }
        int gk = k0 + (tid & 3) * 4;
        float4 v = *(const float4*)(qkv + (long)gm * 1536 + h * 64 + gk);
        r[0]=v.x; r[1]=v.y; r[2]=v.z; r[3]=v.w;
    };
    auto loadK = [&](int k0, float r[4]) {
        int gn = n0 + (tid >> 2);
        if (gn > 400) { r[0]=r[1]=r[2]=r[3]=0.f; return; }
        int gk = k0 + (tid & 3) * 4;
        float4 v = *(const float4*)(qkv + (long)gn * 1536 + 512 + h * 64 + gk);
        r[0]=v.x; r[1]=v.y; r[2]=v.z; r[3]=v.w;
    };
    gemm64<true>(0, 64, tid, as, bs, acc, loadQ, loadK);

    const int tx = tid & 15, ty = tid >> 4;
    const float* Tt = T + (long)h * TSTRIDE;
    float* Sp = S + (long)h * PLANE;
    #pragma unroll
    for (int r = 0; r < 4; ++r) {
        int i = m0 + ty * 4 + r;
        float sv[4];
        #pragma unroll
        for (int c = 0; c < 4; ++c) {
            int j = n0 + tx * 4 + c;
            if (i <= 400 && j <= 400) {
                int id = i * 416 + j;
                int mm = pm[id];
                float fr = pf[id];
                float t0 = Tt[mm], t1 = Tt[mm + 1];
                sv[c] = fmaf(acc[r][c], ATT_SCALE, fmaf(fr, t1 - t0, t0));
                Sp[(long)i * SP + j] = sv[c];
            } else {
                sv[c] = -INFINITY;
            }
        }
        // per-row chunk LSE partial over the 16 tx lanes (64 cols)
        float cmax = fmaxf(fmaxf(sv[0], sv[1]), fmaxf(sv[2], sv[3]));
        cmax = fmaxf(cmax, __shfl_xor(cmax, 1));
        cmax = fmaxf(cmax, __shfl_xor(cmax, 2));
        cmax = fmaxf(cmax, __shfl_xor(cmax, 4));
        cmax = fmaxf(cmax, __shfl_xor(cmax, 8));
        float cs = __expf(sv[0] - cmax) + __expf(sv[1] - cmax)
                 + __expf(sv[2] - cmax) + __expf(sv[3] - cmax);
        cs += __shfl_xor(cs, 1);
        cs += __shfl_xor(cs, 2);
        cs += __shfl_xor(cs, 4);
        cs += __shfl_xor(cs, 8);
        if (tx == 0 && i <= 400) {
            long o = ((long)(h * 401 + i) * 7 + nb) * 2;
            Sml[o] = cmax;
            Sml[o + 1] = cs;
        }
    }
}

// ---------------------------------------------------------------------------
// PV (layer 1), split-K4 over keys, dense V. grid (7,1,32): z = h*4 + sk.
// Prologue merges the 7 per-row LSE partials -> (M, 1/L); A-staging applies
// p = exp(s - M)/L on load (softmax folded in, exact).
// ---------------------------------------------------------------------------
__global__ __launch_bounds__(256) void pv_kernel(
    const float* __restrict__ S, const float* __restrict__ Sml,
    const float* __restrict__ qkv, float* __restrict__ Pv)
{
    __shared__ float as[16][68], bs[16][68];
    __shared__ float rml[64][2];
    const int tid = threadIdx.x;
    const int m0 = blockIdx.x * 64;
    const int h = blockIdx.z >> 2, sk = blockIdx.z & 3;
    const int kBeg = sk * 112;
    const int kEnd = (kBeg + 112 < NP) ? kBeg + 112 : NP;
    float acc[4][4] = {};

    if (tid < 64) {
        int row = m0 + tid;
        float M = -INFINITY, L = 0.f;
        if (row <= 400) {
            const float* q = Sml + ((long)(h * 401 + row) * 7) * 2;
            #pragma unroll
            for (int c = 0; c < 7; ++c) M = fmaxf(M, q[c * 2]);
            #pragma unroll
            for (int c = 0; c < 7; ++c) L += q[c * 2 + 1] * __expf(q[c * 2] - M);
        }
        rml[tid][0] = M;
        rml[tid][1] = (L > 0.f) ? (1.f / L) : 0.f;
    }
    __syncthreads();

    auto loadA = [&](int k0, float r[4]) {
        int gm = m0 + (tid >> 2);
        if (gm > 400) { r[0]=r[1]=r[2]=r[3]=0.f; return; }
        float M = rml[tid >> 2][0], IL = rml[tid >> 2][1];
        int gk = k0 + (tid & 3) * 4;
        const float* p = S + (long)h * PLANE + (long)gm * SP + gk;
        float t4[4] = {-INFINITY, -INFINITY, -INFINITY, -INFINITY};
        if (gk + 3 < kEnd) {
            float4 v = *(const float4*)p;
            t4[0]=v.x; t4[1]=v.y; t4[2]=v.z; t4[3]=v.w;
        } else {
            #pragma unroll
            for (int j = 0; j < 4; ++j) if (gk + j < kEnd) t4[j] = p[j];
        }
        #pragma unroll
        for (int j = 0; j < 4; ++j) r[j] = __expf(t4[j] - M) * IL;
    };
    auto loadB = [&](int k0, float r[4]) {
        r[0] = r[1] = r[2] = r[3] = 0.f;
        int key = k0 + (tid >> 4);
        if (key >= kEnd) return;
        int d = (tid & 15) * 4;
        float4 v = *(const float4*)(qkv + (long)key * 1536 + 1024 + h * 64 + d);
        r[0]=v.x; r[1]=v.y; r[2]=v.z; r[3]=v.w;
    };
    gemm64<false>(kBeg, kEnd, tid, as, bs, acc, loadA, loadB);

    float* C = Pv + (long)sk * PVS;
    const int tx = tid & 15, ty = tid >> 4;
    #pragma unroll
    for (int r = 0; r < 4; ++r) {
        int m = m0 + ty * 4 + r;
        if (m > 400) continue;
        *(float4*)&C[(long)m * 512 + h * 64 + tx * 4] =
            make_float4(acc[r][0], acc[r][1], acc[r][2], acc[r][3]);
    }
}

// ---------------------------------------------------------------------------
// proj (layer 1), split-K8, dense att. grid (7,8,8).
// ---------------------------------------------------------------------------
__global__ __launch_bounds__(256) void proj_kernel(
    const float* __restrict__ att, const float* __restrict__ projw,
    float* __restrict__ Pp)
{
    __shared__ float as[16][68], bs[16][68];
    const int tid = threadIdx.x;
    const int m0 = blockIdx.x * 64, n0 = blockIdx.y * 64, sk = blockIdx.z;
    const int kBeg = sk * 64, kEnd = kBeg + 64;
    float acc[4][4] = {};

    auto loadA = [&](int k0, float r[4]) {
        r[0] = r[1] = r[2] = r[3] = 0.f;
        int gm = m0 + (tid >> 2);
        if (gm > 400) return;
        int gk = k0 + (tid & 3) * 4;
        float4 v = *(const float4*)(att + (long)gm * 512 + gk);
        r[0]=v.x; r[1]=v.y; r[2]=v.z; r[3]=v.w;
    };
    auto loadB = [&](int k0, float r[4]) {
        int gk = k0 + (tid >> 4);
        int gn = n0 + (tid & 15) * 4;
        float4 v = *(const float4*)(projw + (long)gk * 512 + gn);
        r[0]=v.x; r[1]=v.y; r[2]=v.z; r[3]=v.w;
    };
    gemm64<false>(kBeg, kEnd, tid, as, bs, acc, loadA, loadB);

    float* C = Pp + (long)sk * PVS;
    const int tx = tid & 15, ty = tid >> 4;
    #pragma unroll
    for (int r = 0; r < 4; ++r) {
        int m = m0 + ty * 4 + r;
        if (m > 400) continue;
        *(float4*)&C[(long)m * 512 + n0 + tx * 4] =
            make_float4(acc[r][0], acc[r][1], acc[r][2], acc[r][3]);
    }
}

// ---------------------------------------------------------------------------
// Per-row split-K reduce + epilogue + LayerNorm. grid 401.
// ---------------------------------------------------------------------------
__global__ __launch_bounds__(256) void rowfuse_kernel(
    const float* __restrict__ P, long slice, int skN, int rowOff,
    const float* __restrict__ bias, int doRelu,
    const float* __restrict__ resid, const float* __restrict__ cls,
    float* __restrict__ h0,
    const float* __restrict__ g, const float* __restrict__ b,
    float* __restrict__ xln)
{
    const int r = blockIdx.x, t = threadIdx.x;
    float v0, v1;
    if (cls && r == 0) {
        v0 = cls[t]; v1 = cls[t + 256];
    } else {
        const float* p = P + (long)(r - rowOff) * DIM;
        v0 = bias[t]; v1 = bias[t + 256];
        for (int k = 0; k < skN; ++k) {
            v0 += p[(long)k * slice + t];
            v1 += p[(long)k * slice + t + 256];
        }
        if (resid) {
            v0 += resid[(long)r * DIM + t];
            v1 += resid[(long)r * DIM + t + 256];
        }
        if (doRelu) { v0 = fmaxf(v0, 0.f); v1 = fmaxf(v1, 0.f); }
    }
    h0[(long)r * DIM + t] = v0;
    h0[(long)r * DIM + t + 256] = v1;

    float s = v0 + v1, sq = v0 * v0 + v1 * v1;
    #pragma unroll
    for (int off = 32; off > 0; off >>= 1) {
        s += __shfl_down(s, off);
        sq += __shfl_down(sq, off);
    }
    __shared__ float ps[4], pq[4];
    int w = t >> 6, lane = t & 63;
    if (lane == 0) { ps[w] = s; pq[w] = sq; }
    __syncthreads();
    float Sm = ps[0] + ps[1] + ps[2] + ps[3];
    float Q = pq[0] + pq[1] + pq[2] + pq[3];
    float mean = Sm * (1.f / DIM);
    float var = Q * (1.f / DIM) - mean * mean;
    float inv = rsqrtf(var + LN_EPS);
    xln[(long)r * DIM + t]       = (v0 - mean) * inv * g[t] + b[t];
    xln[(long)r * DIM + t + 256] = (v1 - mean) * inv * g[t + 256] + b[t + 256];
}

// ---------------------------------------------------------------------------
// CLS flash-decode (layer 2): grid (8 heads, 7 key-chunks of 64).
// q0 inline from xln row 0; K/V from 4 kv split-K partials + bias inline.
// Also zeroes the cls_proj completion counter (block (0,0)).
// ---------------------------------------------------------------------------
__global__ __launch_bounds__(256) void cls_decode_kernel(
    const float* __restrict__ xln, const float* __restrict__ qkvw,
    const float* __restrict__ Pkv, const float* __restrict__ qkvb,
    const int* __restrict__ pm, const float* __restrict__ pf,
    const float* __restrict__ T,
    float* __restrict__ cms, float* __restrict__ cpv,
    unsigned* __restrict__ cnt)
{
    const int h = blockIdx.x, c = blockIdx.y, tid = threadIdx.x;
    const int kBeg = c * 64;
    __shared__ float q0[64], scraw[64], p[64], red[4][64], rr[2];

    if (h == 0 && c == 0 && tid == 0) *cnt = 0u;   // init for cls_proj

    // q0[d] = sum_k xln[0][k] * Wq[k][h*64+d] + bq[h*64+d]; 4-wave k-split
    {
        int d = tid & 63, w4 = tid >> 6;
        const float* col = qkvw + h * 64 + d;
        float acc = 0.f;
        for (int k = w4 * 128; k < w4 * 128 + 128; ++k)
            acc = fmaf(xln[k], col[(long)k * 1536], acc);
        red[w4][d] = acc;
    }
    __syncthreads();
    if (tid < 64)
        q0[tid] = red[0][tid] + red[1][tid] + red[2][tid] + red[3][tid]
                  + qkvb[h * 64 + tid];
    __syncthreads();

    // scores: key k = tid>>2 (4 lanes/key, 16 dims each), shuffle-reduce
    {
        int k = tid >> 2, q = tid & 3;
        int j = kBeg + k;
        float dot = 0.f;
        if (j < NP) {
            long base = (long)j * 1024 + h * 64 + q * 16;   // K cols 0..512
            #pragma unroll
            for (int d = 0; d < 16; d += 4) {
                float4 x0 = *(const float4*)(Pkv + base + d);
                float4 x1 = *(const float4*)(Pkv + PKS + base + d);
                float4 x2 = *(const float4*)(Pkv + 2 * PKS + base + d);
                float4 x3 = *(const float4*)(Pkv + 3 * PKS + base + d);
                float4 bb = *(const float4*)(qkvb + 512 + h * 64 + q * 16 + d);
                float4 qq = *(const float4*)(q0 + q * 16 + d);
                dot = fmaf(qq.x, x0.x + x1.x + x2.x + x3.x + bb.x, dot);
                dot = fmaf(qq.y, x0.y + x1.y + x2.y + x3.y + bb.y, dot);
                dot = fmaf(qq.z, x0.z + x1.z + x2.z + x3.z + bb.z, dot);
                dot = fmaf(qq.w, x0.w + x1.w + x2.w + x3.w + bb.w, dot);
            }
        }
        dot += __shfl_down(dot, 2);
        dot += __shfl_down(dot, 1);
        if (q == 0) scraw[k] = dot;
    }
    __syncthreads();

    // bias + local softmax on wave 0
    if (tid < 64) {
        int j = kBeg + tid;
        float s;
        if (j < NP) {
            int mm = pm[j];                   // row 0 of pair map
            float fr = pf[j];
            const float* Tt = T + (long)h * TSTRIDE;
            float t0 = Tt[mm], t1 = Tt[mm + 1];
            s = fmaf(scraw[tid], ATT_SCALE, fmaf(fr, t1 - t0, t0));
        } else {
            s = -INFINITY;
        }
        float m = s;
        #pragma unroll
        for (int off = 32; off > 0; off >>= 1)
            m = fmaxf(m, __shfl_xor(m, off));
        float e = (j < NP) ? __expf(s - m) : 0.f;
        float sum = e;
        #pragma unroll
        for (int off = 32; off > 0; off >>= 1)
            sum += __shfl_xor(sum, off);
        p[tid] = e;
        if (tid == 0) { rr[0] = m; rr[1] = sum; }
    }
    __syncthreads();

    // partial PV: d = lane, wave w handles keys k ≡ w (mod 4)
    {
        int w = tid >> 6, d = tid & 63;
        float vb = qkvb[1024 + h * 64 + d];
        float acc = 0.f;
        for (int k = w; k < 64; k += 4) {
            int j = kBeg + k;
            if (j >= NP) break;
            long o = (long)j * 1024 + 512 + h * 64 + d;     // V cols 512..1024
            float v = Pkv[o] + Pkv[PKS + o] + Pkv[2 * PKS + o]
                      + Pkv[3 * PKS + o] + vb;
            acc = fmaf(p[k], v, acc);
        }
        red[w][d] = acc;
    }
    __syncthreads();
    if (tid < 64) {
        cpv[((long)h * 7 + c) * 64 + tid] =
            red[0][tid] + red[1][tid] + red[2][tid] + red[3][tid];
        if (tid == 0) {
            cms[(h * 7 + c) * 2 + 0] = rr[0];
            cms[(h * 7 + c) * 2 + 1] = rr[1];
        }
    }
}

// ---------------------------------------------------------------------------
// CLS proj (inlined LSE combine) + last-block fused residual+LN+fc2 -> out.
// grid 8 x 256 thr.
// ---------------------------------------------------------------------------
__global__ __launch_bounds__(256) void cls_proj_kernel(
    const float* __restrict__ cms, const float* __restrict__ cpv,
    const float* __restrict__ projw, const float* __restrict__ projb,
    float* __restrict__ proj0,
    const float* __restrict__ h0,
    const float* __restrict__ g, const float* __restrict__ b,
    const float* __restrict__ fc2w, const float* __restrict__ fc2b,
    float* __restrict__ out, unsigned* __restrict__ cnt)
{
    __shared__ float av[512], red[4][64];
    __shared__ int isLast;
    const int bk = blockIdx.x, tid = threadIdx.x;
    for (int d = tid; d < 512; d += 256) {
        int h = d >> 6, dd = d & 63;
        float M = -INFINITY;
        #pragma unroll
        for (int c = 0; c < 7; ++c)
            M = fmaxf(M, cms[(h * 7 + c) * 2]);
        float Sx = 0.f, acc = 0.f;
        #pragma unroll
        for (int c = 0; c < 7; ++c) {
            float e = __expf(cms[(h * 7 + c) * 2] - M);
            Sx += cms[(h * 7 + c) * 2 + 1] * e;
            acc += cpv[((long)h * 7 + c) * 64 + dd] * e;
        }
        av[d] = acc / Sx;
    }
    __syncthreads();
    int gg = tid >> 6, n = bk * 64 + (tid & 63);
    float acc = 0.f;
    for (int k = gg * 128; k < gg * 128 + 128; ++k)
        acc = fmaf(av[k], projw[(long)k * 512 + n], acc);
    red[gg][tid & 63] = acc;
    __syncthreads();
    if (tid < 64)
        proj0[bk * 64 + tid] = red[0][tid] + red[1][tid] + red[2][tid]
                               + red[3][tid] + projb[bk * 64 + tid];

    // last-block: residual + LN + fc2 -> out
    __threadfence();
    if (tid == 0) isLast = (atomicAdd(cnt, 1u) == 7u);
    __syncthreads();
    if (!isLast) return;
    __threadfence();

    const int t = tid;
    float v0 = h0[t] + proj0[t];
    float v1 = h0[t + 256] + proj0[t + 256];
    float s = v0 + v1, sq = v0 * v0 + v1 * v1;
    #pragma unroll
    for (int off = 32; off > 0; off >>= 1) {
        s += __shfl_down(s, off);
        sq += __shfl_down(sq, off);
    }
    __shared__ float ps[4], pq[4], pc0[4], pc1[4];
    int w = t >> 6, lane = t & 63;
    if (lane == 0) { ps[w] = s; pq[w] = sq; }
    __syncthreads();
    float Sm = ps[0] + ps[1] + ps[2] + ps[3];
    float Q = pq[0] + pq[1] + pq[2] + pq[3];
    float mean = Sm * (1.f / DIM);
    float var = Q * (1.f / DIM) - mean * mean;
    float inv = rsqrtf(var + LN_EPS);
    float n0 = (v0 - mean) * inv * g[t] + b[t];
    float n1 = (v1 - mean) * inv * g[t + 256] + b[t + 256];
    float c0 = n0 * fc2w[t * 2]     + n1 * fc2w[(t + 256) * 2];
    float c1 = n0 * fc2w[t * 2 + 1] + n1 * fc2w[(t + 256) * 2 + 1];
    #pragma unroll
    for (int off = 32; off > 0; off >>= 1) {
        c0 += __shfl_down(c0, off);
        c1 += __shfl_down(c1, off);
    }
    if (lane == 0) { pc0[w] = c0; pc1[w] = c1; }
    __syncthreads();
    if (t == 0) {
        out[0] = pc0[0] + pc0[1] + pc0[2] + pc0[3] + fc2b[0];
        out[1] = pc1[0] + pc1[1] + pc1[2] + pc1[3] + fc2b[1];
    }
}

// ---------------------------------------------------------------------------
// Mega init: [0,896) fc1 split-K16 -> Pp; [896,1026) CPB angle tables
// (65 blocks/layer at CPB_M=4096); [1026,1655) pair -> (angle idx, frac).
// ---------------------------------------------------------------------------
__global__ __launch_bounds__(256) void mega_kernel(
    const float* __restrict__ hin, const float* __restrict__ fc1_w,
    const float* __restrict__ w1_0, const float* __restrict__ b1_0,
    const float* __restrict__ w2_0, const float* __restrict__ b2_0,
    const float* __restrict__ w1_1, const float* __restrict__ b1_1,
    const float* __restrict__ w2_1, const float* __restrict__ b2_1,
    const float* __restrict__ coords,
    float* __restrict__ Pp, float* __restrict__ T,
    int* __restrict__ pm, float* __restrict__ pf)
{
    __shared__ float smem[2176];
    float (*as)[68] = (float(*)[68])smem;
    float (*bs)[68] = (float(*)[68])(smem + 1088);
    float (*red)[64][8] = (float(*)[64][8])smem;
    const int bid = blockIdx.x, tid = threadIdx.x;

    if (bid < 896) {
        int sk = bid / 56, rem = bid % 56;
        int m0 = (rem % 7) * 64, n0 = (rem / 7) * 64;
        int kBeg = sk * 64, kEnd = kBeg + 64;
        float acc[4][4] = {};
        auto loadA = [&](int k0, float r[4]) {
            r[0]=r[1]=r[2]=r[3]=0.f;
            int gm = m0 + (tid >> 2);
            if (gm >= 400) return;
            int gk = k0 + (tid & 3) * 4;
            float4 v = *(const float4*)(hin + (long)gm * 1024 + gk);
            r[0]=v.x; r[1]=v.y; r[2]=v.z; r[3]=v.w;
        };
        auto loadB = [&](int k0, float r[4]) {
            int gk = k0 + (tid >> 4);
            int gn = n0 + (tid & 15) * 4;
            float4 v = *(const float4*)(fc1_w + (long)gk * 512 + gn);
            r[0]=v.x; r[1]=v.y; r[2]=v.z; r[3]=v.w;
        };
        gemm64<false>(kBeg, kEnd, tid, as, bs, acc, loadA, loadB);
        float* C = Pp + (long)sk * PVS;
        const int tx = tid & 15, ty = tid >> 4;
        #pragma unroll
        for (int r = 0; r < 4; ++r) {
            int m = m0 + ty * 4 + r;
            if (m >= 400) continue;
            *(float4*)&C[(long)m * 512 + n0 + tx * 4] =
                make_float4(acc[r][0], acc[r][1], acc[r][2], acc[r][3]);
        }
    } else if (bid < 1026) {
        int tb = bid - 896;
        int z = tb / 65, ab = tb % 65;
        const float* w1 = z ? w1_1 : w1_0;
        const float* b1 = z ? b1_1 : b1_0;
        const float* w2 = z ? w2_1 : w2_0;
        const float* b2 = z ? b2_1 : b2_0;
        const int lane = tid & 63, wv = tid >> 6;
        float ca = 0.f, sa = 0.f;
        if (ab != 64) {
            float th = fmaf((float)(ab * 64 + lane),
                            (float)(2.0 * M_PI / CPB_M), -(float)M_PI);
            sincosf(th, &sa, &ca);
        } else if (lane == 0) {
            sincosf((float)M_PI, &sa, &ca);  // wrap row; lanes>0 zero-vec
        }
        float a8[8] = {};
        const int kbeg = wv * 128;
        #pragma unroll 4
        for (int k = kbeg; k < kbeg + 128; ++k) {
            float hk = fmaxf(fmaf(ca, w1[k],
                                  fmaf(sa, w1[512 + k], b1[k])), 0.f);
            #pragma unroll
            for (int h2 = 0; h2 < 8; ++h2)
                a8[h2] = fmaf(hk, w2[k * 8 + h2], a8[h2]);
        }
        #pragma unroll
        for (int h2 = 0; h2 < 8; ++h2) red[wv][lane][h2] = a8[h2];
        __syncthreads();
        if (tid < 64) {
            int aidx = ab * 64 + tid;
            if (aidx <= CPB_M + 1) {
                #pragma unroll
                for (int h2 = 0; h2 < 8; ++h2)
                    T[(long)(z * 8 + h2) * TSTRIDE + aidx] =
                        red[0][tid][h2] + red[1][tid][h2] +
                        red[2][tid][h2] + red[3][tid][h2] + b2[h2];
            }
        }
    } else {
        int p = (bid - 1026) * 256 + tid;
        if (p < NP * NP) {
            int i = p / NP, j = p - i * NP;
            float xi = (i == 0) ? 0.f : coords[(i - 1) * 2];
            float yi = (i == 0) ? 0.f : coords[(i - 1) * 2 + 1];
            float xj = (j == 0) ? 0.f : coords[(j - 1) * 2];
            float yj = (j == 0) ? 0.f : coords[(j - 1) * 2 + 1];
            float rx = xi - xj, ry = yi - yj;
            int mm; float fr;
            if (rx == 0.f && ry == 0.f) {
                mm = CPB_M + 1; fr = 0.f;
            } else {
                float x = (atan2f(ry, rx) + 3.14159265358979f)
                          * (float)(CPB_M / (2.0 * M_PI));
                int mi = (int)x;
                fr = x - (float)mi;
                mm = (mi >= CPB_M) ? mi - CPB_M : mi;
            }
            pm[i * 416 + j] = mm;
            pf[i * 416 + j] = fr;
        }
    }
}

// ---------------------------------------------------------------------------
extern "C" void kernel_launch(void* const* d_in, const int* in_sizes, int n_in,
                              void* d_out, int out_size, void* d_ws, size_t ws_size,
                              hipStream_t stream)
{
    const float* coords = (const float*)d_in[1];
    float* ws = (float*)d_ws;
    float* h0   = ws;                    ws += 401L * 512;
    float* xln  = ws;                    ws += 401L * 512;
    float* S    = ws;                    ws += 8L * PLANE;
    float* T    = ws;                    ws += 16L * TSTRIDE;
    int*   pm   = (int*)ws;              ws += 401L * 416;
    float* pf   = ws;                    ws += 401L * 416;
    float* Pq   = ws;                    ws += 4L * PQS;   // also layer-2 kv
    float* qkv  = ws;                    ws += 401L * 1536;
    float* Pv   = ws;                    ws += 4L * PVS;
    float* att  = ws;                    ws += 401L * 512;
    float* Pp   = ws;                    ws += 16L * PVS;
    float* proj0 = ws;                   ws += 512;
    float* cms  = ws;                    ws += 8L * 7 * 2;
    float* cpv  = ws;                    ws += 8L * 7 * 64;
    float* Sml  = ws;                    ws += 8L * 401 * 7 * 2;
    unsigned* cnt = (unsigned*)ws;       ws += 16;

    // phase 0: fc1 (K16) + both CPB angle tables + pair->angle map
    mega_kernel<<<1655, 256, 0, stream>>>(
        (const float*)d_in[0], (const float*)d_in[2],
        (const float*)d_in[7],  (const float*)d_in[8],
        (const float*)d_in[9],  (const float*)d_in[10],
        (const float*)d_in[17], (const float*)d_in[18],
        (const float*)d_in[19], (const float*)d_in[20],
        coords, Pp, T, pm, pf);

    // fc1 reduce + relu + cls + LN(l1) -> h0, xln
    rowfuse_kernel<<<401, 256, 0, stream>>>(
        Pp, PVS, 16, 1, (const float*)d_in[3], 1, nullptr,
        (const float*)d_in[4], h0,
        (const float*)d_in[5], (const float*)d_in[6], xln);

    // -------- layer 1 (full attention; softmax folded into qk+pv) --------
    gemm_split_kernel<<<dim3(7, 24, 4), 256, 0, stream>>>(
        xln, 512, (const float*)d_in[11], 1536, Pq, 1536, PQS,
        401, 1536, 512, 4);
    reduce_kernel<<<602, 256, 0, stream>>>(
        Pq, PQS, 4, (const float*)d_in[12], qkv, 401 * 1536, 1536);
    qk_kernel<<<dim3(7, 7, 8), 256, 0, stream>>>(qkv, pm, pf, T, S, Sml);
    pv_kernel<<<dim3(7, 1, 32), 256, 0, stream>>>(S, Sml, qkv, Pv);
    reduce_kernel<<<201, 256, 0, stream>>>(
        Pv, PVS, 4, nullptr, att, 401 * 512, 512);
    proj_kernel<<<dim3(7, 8, 8), 256, 0, stream>>>(
        att, (const float*)d_in[13], Pp);
    rowfuse_kernel<<<401, 256, 0, stream>>>(
        Pp, PVS, 8, 0, (const float*)d_in[14], 0, h0, nullptr, h0,
        (const float*)d_in[15], (const float*)d_in[16], xln);

    // -------- layer 2: K,V only GEMM (cols 512..1536), CLS flash-decode ----
    gemm_split_kernel<<<dim3(7, 16, 4), 256, 0, stream>>>(
        xln, 512, (const float*)d_in[21] + 512, 1536, Pq, 1024, PKS,
        401, 1024, 512, 4);
    cls_decode_kernel<<<dim3(8, 7), 256, 0, stream>>>(
        xln, (const float*)d_in[21], Pq, (const float*)d_in[22],
        pm, pf, T + 8L * TSTRIDE, cms, cpv, cnt);
    cls_proj_kernel<<<8, 256, 0, stream>>>(
        cms, cpv, (const float*)d_in[23], (const float*)d_in[24], proj0,
        h0, (const float*)d_in[25], (const float*)d_in[26],
        (const float*)d_in[27], (const float*)d_in[28], (float*)d_out, cnt);
}